// Round 1
// baseline (3321.644 us; speedup 1.0000x reference)
//
#include <hip/hip_runtime.h>
#include <math.h>

namespace {
constexpr int kB = 8;
constexpr int kL = 2048;
constexpr int kD = 512;
constexpr int kDff = 2048;
constexpr int kTopk = 15;
constexpr int kLMask = 2047;
}

// C[M,N] = A[M,K] @ B (+bias) (+Res) (relu?)
// BT=0: B is [K,N] row-major; BT=1: B is [N,K] row-major (C = A @ B^T)
template<int BT, int RELU>
__global__ __launch_bounds__(256)
void gemm_kernel(const float* __restrict__ A, const float* __restrict__ Bm,
                 const float* __restrict__ bias, const float* __restrict__ Res,
                 float* __restrict__ C, int M, int N, int K) {
  __shared__ float As[8][128];
  __shared__ float Bs[8][128];
  const int tid = threadIdx.x;
  const int bm = blockIdx.y * 128;
  const int bn = blockIdx.x * 128;
  const int tx = tid & 15;
  const int ty = tid >> 4;
  const int lrow = tid >> 1;
  const int lk = (tid & 1) * 4;
  float acc[8][8];
#pragma unroll
  for (int r = 0; r < 8; ++r)
#pragma unroll
    for (int c = 0; c < 8; ++c) acc[r][c] = 0.f;

  for (int k0 = 0; k0 < K; k0 += 8) {
    float4 av = *(const float4*)(A + (size_t)(bm + lrow) * K + k0 + lk);
    As[lk + 0][lrow] = av.x;
    As[lk + 1][lrow] = av.y;
    As[lk + 2][lrow] = av.z;
    As[lk + 3][lrow] = av.w;
    if (BT) {
      float4 bv = *(const float4*)(Bm + (size_t)(bn + lrow) * K + k0 + lk);
      Bs[lk + 0][lrow] = bv.x;
      Bs[lk + 1][lrow] = bv.y;
      Bs[lk + 2][lrow] = bv.z;
      Bs[lk + 3][lrow] = bv.w;
    } else {
      const int bk = tid >> 5;
      const int bj = (tid & 31) * 4;
      *(float4*)&Bs[bk][bj] = *(const float4*)(Bm + (size_t)(k0 + bk) * N + bn + bj);
    }
    __syncthreads();
#pragma unroll
    for (int kk = 0; kk < 8; ++kk) {
      float a[8], b[8];
      *(float4*)&a[0] = *(const float4*)&As[kk][ty * 8];
      *(float4*)&a[4] = *(const float4*)&As[kk][ty * 8 + 4];
      *(float4*)&b[0] = *(const float4*)&Bs[kk][tx * 8];
      *(float4*)&b[4] = *(const float4*)&Bs[kk][tx * 8 + 4];
#pragma unroll
      for (int r = 0; r < 8; ++r)
#pragma unroll
        for (int c = 0; c < 8; ++c) acc[r][c] += a[r] * b[c];
    }
    __syncthreads();
  }

#pragma unroll
  for (int r = 0; r < 8; ++r) {
    const int row = bm + ty * 8 + r;
#pragma unroll
    for (int c = 0; c < 8; ++c) {
      const int col = bn + tx * 8 + c;
      float v = acc[r][c];
      if (bias) v += bias[col];
      if (Res) v += Res[(size_t)row * N + col];
      if (RELU) v = v > 0.f ? v : 0.f;
      C[(size_t)row * N + col] = v;
    }
  }
}

// Sum diagonals (i-j=const -> csig) and anti-diagonals (i+j=const -> wsig) of
// one batch's R = q_b @ k_b^T, accumulated circularly mod L.
__global__ __launch_bounds__(256)
void diag_reduce_kernel(const float* __restrict__ R, float* __restrict__ csig,
                        float* __restrict__ wsig, int b) {
  __shared__ float s[64][65];
  const int i0 = blockIdx.y * 64;
  const int j0 = blockIdx.x * 64;
  for (int e = threadIdx.x; e < 4096; e += 256) {
    const int i = e >> 6, j = e & 63;
    s[i][j] = R[(size_t)(i0 + i) * kL + (j0 + j)];
  }
  __syncthreads();
  // c(tau): tau = (i - j) mod L
  for (int dd = threadIdx.x; dd < 127; dd += 256) {
    const int d = dd - 63;
    const int ilo = d < 0 ? 0 : d;
    const int ihi = d < 0 ? 63 + d : 63;
    float sum = 0.f;
    for (int i = ilo; i <= ihi; ++i) sum += s[i][i - d];
    const int tau = (i0 - j0 + d + 2 * kL) & kLMask;
    atomicAdd(&csig[b * kL + tau], sum);
  }
  // w(tau): tau = (i + j) mod L
  for (int ss = threadIdx.x; ss < 127; ss += 256) {
    const int ilo = ss < 64 ? 0 : ss - 63;
    const int ihi = ss < 64 ? ss : 63;
    float sum = 0.f;
    for (int i = ilo; i <= ihi; ++i) sum += s[i][ss - i];
    const int tau = (i0 + j0 + ss) & kLMask;
    atomicAdd(&wsig[b * kL + tau], sum);
  }
}

// A[f] = sum_tau (c+w)/2 * cos(2pi f tau/L); Bs[f] = sum_tau (c-w)/2 * cos(...)
__global__ __launch_bounds__(256)
void dft_kernel(const float* __restrict__ csig, const float* __restrict__ wsig,
                float* __restrict__ Asp, float* __restrict__ Bsp) {
  __shared__ float cp[kL];
  __shared__ float cm[kL];
  __shared__ float ct[kL];
  const int b = blockIdx.y;
  const int f = blockIdx.x * 256 + threadIdx.x;
  for (int e = threadIdx.x; e < kL; e += 256) {
    const float cv = csig[b * kL + e];
    const float wv = wsig[b * kL + e];
    cp[e] = 0.5f * (cv + wv);
    cm[e] = 0.5f * (cv - wv);
    ct[e] = cosf((float)e * (6.283185307179586f / 2048.0f));
  }
  __syncthreads();
  if (f <= kL / 2) {
    float a = 0.f, bb = 0.f;
    for (int t = 0; t < kL; ++t) {
      const float w = ct[(f * t) & kLMask];
      a += cp[t] * w;
      bb += cm[t] * w;
    }
    Asp[b * 1025 + f] = a;
    Bsp[b * 1025 + f] = bb;
  }
}

// mean_value[b][tau] = irfft(A - iB)(tau) / 512
__global__ __launch_bounds__(256)
void imean_kernel(const float* __restrict__ Asp, const float* __restrict__ Bsp,
                  float* __restrict__ meanv) {
  __shared__ float sA[1025];
  __shared__ float sB[1025];
  __shared__ float ct[kL];
  __shared__ float st[kL];
  const int b = blockIdx.y;
  const int tau = blockIdx.x * 256 + threadIdx.x;
  for (int e = threadIdx.x; e < kL; e += 256) {
    float sv, cv;
    __sincosf((float)e * (6.283185307179586f / 2048.0f), &sv, &cv);
    ct[e] = cv;
    st[e] = sv;
    if (e < 1025) {
      sA[e] = Asp[b * 1025 + e];
      sB[e] = Bsp[b * 1025 + e];
    }
  }
  __syncthreads();
  float sum = sA[0] + ((tau & 1) ? -sA[1024] : sA[1024]);
  for (int f = 1; f < 1024; ++f) {
    const int r = (f * tau) & kLMask;
    sum += 2.f * (sA[f] * ct[r] + sB[f] * st[r]);
  }
  meanv[b * kL + tau] = sum * (1.0f / 1048576.0f);  // 1/(512*2048)
}

// top-15 (desc, ties -> lower index) + softmax
__global__ __launch_bounds__(256)
void topk_kernel(const float* __restrict__ meanv, float* __restrict__ wts,
                 int* __restrict__ dly) {
  __shared__ float f[kL];
  __shared__ float rv[256];
  __shared__ int ri[256];
  __shared__ float topv[kTopk];
  __shared__ int topi[kTopk];
  const int b = blockIdx.x;
  const int t = threadIdx.x;
  for (int e = t; e < kL; e += 256) f[e] = meanv[b * kL + e];
  __syncthreads();
  for (int round = 0; round < kTopk; ++round) {
    float bv = -INFINITY;
    int bi = 1 << 30;
    for (int e = t; e < kL; e += 256) {
      const float v = f[e];
      if (v > bv || (v == bv && e < bi)) { bv = v; bi = e; }
    }
    rv[t] = bv; ri[t] = bi;
    __syncthreads();
    for (int s = 128; s > 0; s >>= 1) {
      if (t < s) {
        const float v2 = rv[t + s];
        const int i2 = ri[t + s];
        if (v2 > rv[t] || (v2 == rv[t] && i2 < ri[t])) { rv[t] = v2; ri[t] = i2; }
      }
      __syncthreads();
    }
    if (t == 0) {
      topv[round] = rv[0];
      topi[round] = ri[0];
      f[ri[0]] = -INFINITY;
    }
    __syncthreads();
  }
  if (t == 0) {
    const float m = topv[0];
    float sum = 0.f;
    float e[kTopk];
    for (int i = 0; i < kTopk; ++i) { e[i] = expf(topv[i] - m); sum += e[i]; }
    for (int i = 0; i < kTopk; ++i) {
      wts[b * 16 + i] = e[i] / sum;
      dly[b * 16 + i] = topi[i];
    }
  }
}

// attn_in[b,l,c] = sum_t w_t * v[b,(l+delay_t)%L,c]
__global__ __launch_bounds__(256)
void agg_kernel(const float* __restrict__ v, const float* __restrict__ wts,
                const int* __restrict__ dly, float* __restrict__ out) {
  __shared__ float w[kTopk];
  __shared__ int dl[kTopk];
  const int l = blockIdx.x;
  const int b = blockIdx.y;
  if (threadIdx.x < kTopk) {
    w[threadIdx.x] = wts[b * 16 + threadIdx.x];
    dl[threadIdx.x] = dly[b * 16 + threadIdx.x];
  }
  __syncthreads();
  const float* vb = v + (size_t)b * kL * kD;
  const int c0 = threadIdx.x;
  const int c1 = threadIdx.x + 256;
  float a0 = 0.f, a1 = 0.f;
  for (int t = 0; t < kTopk; ++t) {
    const int row = (l + dl[t]) & kLMask;
    const float* vr = vb + (size_t)row * kD;
    a0 += w[t] * vr[c0];
    a1 += w[t] * vr[c1];
  }
  float* o = out + ((size_t)b * kL + l) * kD;
  o[c0] = a0;
  o[c1] = a1;
}

// out = x - centered 25-tap clamped moving average of x
__global__ __launch_bounds__(256)
void decomp_kernel(const float* __restrict__ X, float* __restrict__ Out, int total) {
  const int idx = blockIdx.x * 256 + threadIdx.x;
  if (idx >= total) return;
  const int c = idx & (kD - 1);
  const int l = (idx / kD) & kLMask;
  const int b = idx / (kD * kL);
  const float* base = X + (size_t)b * kL * kD + c;
  float s = 0.f;
#pragma unroll
  for (int m = -12; m <= 12; ++m) {
    int lm = l + m;
    lm = lm < 0 ? 0 : (lm > kL - 1 ? kL - 1 : lm);
    s += base[(size_t)lm * kD];
  }
  Out[idx] = X[idx] - s * (1.0f / 25.0f);
}

extern "C" void kernel_launch(void* const* d_in, const int* in_sizes, int n_in,
                              void* d_out, int out_size, void* d_ws, size_t ws_size,
                              hipStream_t stream) {
  const float* x  = (const float*)d_in[0];
  const float* Wq = (const float*)d_in[1];
  const float* bq = (const float*)d_in[2];
  const float* Wk = (const float*)d_in[3];
  const float* bk = (const float*)d_in[4];
  const float* Wv = (const float*)d_in[5];
  const float* bv = (const float*)d_in[6];
  const float* Wo = (const float*)d_in[7];
  const float* bo = (const float*)d_in[8];
  const float* W1 = (const float*)d_in[9];
  const float* W2 = (const float*)d_in[10];
  float* out = (float*)d_out;

  const size_t NBLD = (size_t)kB * kL * kD;  // 8,388,608 floats
  float* bufQ  = (float*)d_ws;               // q proj -> later attn_in
  float* bufK  = bufQ + NBLD;                // k proj -> later s2pre
  float* bufV  = bufK + NBLD;                // v proj -> later xr
  float* bufS1 = bufV + NBLD;                // s1
  float* bufM  = bufS1 + NBLD;               // FFN mid chunk (4096 x 2048)
  float* bufR  = bufM + NBLD;                // per-batch Gram (2048 x 2048)
  float* csig  = bufR + (size_t)kL * kL;     // 8 x 2048
  float* wsig  = csig + kB * kL;             // 8 x 2048 (contiguous with csig)
  float* Asp   = wsig + kB * kL;             // 8 x 1025
  float* Bsp   = Asp + kB * 1025;
  float* wtsf  = Bsp + kB * 1025;            // 8 x 16
  int*   dlyi  = (int*)(wtsf + kB * 16);     // 8 x 16

  const dim3 blk(256);
  const int M = kB * kL;  // 16384

  // Q/K/V projections
  gemm_kernel<0, 0><<<dim3(4, 128), blk, 0, stream>>>(x, Wq, bq, nullptr, bufQ, M, kD, kD);
  gemm_kernel<0, 0><<<dim3(4, 128), blk, 0, stream>>>(x, Wk, bk, nullptr, bufK, M, kD, kD);
  gemm_kernel<0, 0><<<dim3(4, 128), blk, 0, stream>>>(x, Wv, bv, nullptr, bufV, M, kD, kD);

  // correlation signals via per-batch Gram matrix
  hipMemsetAsync(csig, 0, 2 * kB * kL * sizeof(float), stream);
  for (int b = 0; b < kB; ++b) {
    gemm_kernel<1, 0><<<dim3(16, 16), blk, 0, stream>>>(
        bufQ + (size_t)b * kL * kD, bufK + (size_t)b * kL * kD, nullptr, nullptr,
        bufR, kL, kL, kD);
    diag_reduce_kernel<<<dim3(32, 32), blk, 0, stream>>>(bufR, csig, wsig, b);
  }
  dft_kernel<<<dim3(5, kB), blk, 0, stream>>>(csig, wsig, Asp, Bsp);
  imean_kernel<<<dim3(8, kB), blk, 0, stream>>>(Asp, Bsp, csig /*reuse as meanv*/);
  topk_kernel<<<kB, blk, 0, stream>>>(csig, wtsf, dlyi);

  // delay aggregation (into bufQ) then output proj + residual -> xr (bufV)
  agg_kernel<<<dim3(kL, kB), blk, 0, stream>>>(bufV, wtsf, dlyi, bufQ);
  gemm_kernel<0, 0><<<dim3(4, 128), blk, 0, stream>>>(bufQ, Wo, bo, x, bufV, M, kD, kD);

  // decomp 1: s1 = xr - trend(xr)
  decomp_kernel<<<(int)(NBLD / 256), blk, 0, stream>>>(bufV, bufS1, (int)NBLD);

  // FFN in 4 row-chunks of 4096: s2pre = relu(s1@W1)@W2 + s1  (into bufK)
  for (int r0 = 0; r0 < M; r0 += 4096) {
    gemm_kernel<0, 1><<<dim3(16, 32), blk, 0, stream>>>(
        bufS1 + (size_t)r0 * kD, W1, nullptr, nullptr, bufM, 4096, kDff, kD);
    gemm_kernel<0, 0><<<dim3(4, 32), blk, 0, stream>>>(
        bufM, W2, nullptr, bufS1 + (size_t)r0 * kD, bufK + (size_t)r0 * kD,
        4096, kD, kDff);
  }

  // decomp 2 -> output
  decomp_kernel<<<(int)(NBLD / 256), blk, 0, stream>>>(bufK, out, (int)NBLD);
}

// Round 2
// 685.774 us; speedup vs baseline: 4.8436x; 4.8436x over previous
//
#include <hip/hip_runtime.h>
#include <math.h>

namespace {
constexpr int kB = 8;
constexpr int kL = 2048;
constexpr int kD = 512;
constexpr int kDff = 2048;
constexpr int kTopk = 15;
constexpr int kLMask = 2047;
}

typedef unsigned short u16;
using f32x4 = __attribute__((ext_vector_type(4))) float;
using bf16x8 = __attribute__((ext_vector_type(8))) __bf16;

__device__ __forceinline__ u16 f2b(float f) {
  unsigned u = __float_as_uint(f);
  unsigned r = (u + 0x7fffu + ((u >> 16) & 1u)) >> 16;  // RNE
  return (u16)r;
}
__device__ __forceinline__ float b2f(u16 u) {
  return __uint_as_float(((unsigned)u) << 16);
}

// ---------------------------------------------------------------------------
// bf16 MFMA GEMM: C[M,N] = A[M,K] @ Bt[N,K]^T  (+bias)(+Res fp32)(relu)
// 128x128 tile, 256 threads = 4 waves, each wave 64x64 via 4x4 of 16x16x32.
// Batched via blockIdx.z with element strides sA,sB,sC (0 for unbatched).
// ---------------------------------------------------------------------------
template <int RELU, int OUTF, int OUTB>
__global__ __launch_bounds__(256)
void mfma_gemm(const u16* __restrict__ A, const u16* __restrict__ Bt,
               const float* __restrict__ bias, const float* __restrict__ Res,
               float* __restrict__ outF, u16* __restrict__ outB,
               int M, int N, int K, size_t sA, size_t sB, size_t sC) {
  __shared__ u16 As[128][40];  // 32 + 8 pad
  __shared__ u16 Bs[128][40];
  const int tid = threadIdx.x;
  const int bm = blockIdx.y * 128;
  const int bn = blockIdx.x * 128;
  const size_t zA = (size_t)blockIdx.z * sA;
  const size_t zB = (size_t)blockIdx.z * sB;
  const size_t zC = (size_t)blockIdx.z * sC;
  const int wave = tid >> 6;
  const int lane = tid & 63;
  const int wm = (wave >> 1) * 64;
  const int wn = (wave & 1) * 64;
  const int ln = lane & 15;
  const int quad = lane >> 4;
  const int srow = tid >> 2;         // staging: 64 rows per pass
  const int scol = (tid & 3) * 8;    // 8 bf16 = 16B chunks

  f32x4 zero = {0.f, 0.f, 0.f, 0.f};
  f32x4 acc[4][4];
#pragma unroll
  for (int i = 0; i < 4; ++i)
#pragma unroll
    for (int j = 0; j < 4; ++j) acc[i][j] = zero;

  for (int k0 = 0; k0 < K; k0 += 32) {
#pragma unroll
    for (int c = 0; c < 2; ++c) {
      const int row = c * 64 + srow;
      float4 va = *(const float4*)(A + zA + (size_t)(bm + row) * K + k0 + scol);
      *(float4*)&As[row][scol] = va;
      float4 vb = *(const float4*)(Bt + zB + (size_t)(bn + row) * K + k0 + scol);
      *(float4*)&Bs[row][scol] = vb;
    }
    __syncthreads();
    bf16x8 af[4], bf[4];
#pragma unroll
    for (int i = 0; i < 4; ++i)
      af[i] = *(const bf16x8*)&As[wm + i * 16 + ln][quad * 8];
#pragma unroll
    for (int j = 0; j < 4; ++j)
      bf[j] = *(const bf16x8*)&Bs[wn + j * 16 + ln][quad * 8];
#pragma unroll
    for (int i = 0; i < 4; ++i)
#pragma unroll
      for (int j = 0; j < 4; ++j)
        acc[i][j] = __builtin_amdgcn_mfma_f32_16x16x32_bf16(af[i], bf[j], acc[i][j], 0, 0, 0);
    __syncthreads();
  }

#pragma unroll
  for (int i = 0; i < 4; ++i) {
#pragma unroll
    for (int r = 0; r < 4; ++r) {
      const int row = bm + wm + i * 16 + quad * 4 + r;
#pragma unroll
      for (int j = 0; j < 4; ++j) {
        const int col = bn + wn + j * 16 + ln;
        float v = acc[i][j][r];
        if (bias) v += bias[col];
        if (Res) v += Res[(size_t)row * N + col];
        if (RELU) v = fmaxf(v, 0.f);
        if (OUTF) outF[zC + (size_t)row * N + col] = v;
        if (OUTB) outB[zC + (size_t)row * N + col] = f2b(v);
      }
    }
  }
}

// cast fp32 -> bf16, 4 elements/thread
__global__ __launch_bounds__(256)
void cast_f2b_kernel(const float* __restrict__ X, u16* __restrict__ Y) {
  const int i = (blockIdx.x * 256 + threadIdx.x) * 4;
  float4 v = *(const float4*)(X + i);
  ushort4 o;
  o.x = f2b(v.x); o.y = f2b(v.y); o.z = f2b(v.z); o.w = f2b(v.w);
  *(ushort4*)(Y + i) = o;
}

// W[K][N] (fp32) -> Wt[N][K] (bf16)
__global__ __launch_bounds__(256)
void transpose_cast_kernel(const float* __restrict__ W, u16* __restrict__ Wt,
                           int K, int N) {
  __shared__ float t[32][33];
  const int k0 = blockIdx.y * 32, n0 = blockIdx.x * 32;
  const int tx = threadIdx.x & 31, ty = threadIdx.x >> 5;
  for (int r = ty; r < 32; r += 8)
    t[r][tx] = W[(size_t)(k0 + r) * N + n0 + tx];
  __syncthreads();
  for (int r = ty; r < 32; r += 8)
    Wt[(size_t)(n0 + r) * K + k0 + tx] = f2b(t[tx][r]);
}

// Diagonal/anti-diagonal sums of Gram tiles (batched over blockIdx.z)
__global__ __launch_bounds__(256)
void diag_reduce_kernel(const float* __restrict__ Rbase, float* __restrict__ csig,
                        float* __restrict__ wsig, int bbase) {
  __shared__ float s[64][65];
  const float* R = Rbase + (size_t)blockIdx.z * kL * kL;
  const int b = bbase + blockIdx.z;
  const int i0 = blockIdx.y * 64;
  const int j0 = blockIdx.x * 64;
  for (int e = threadIdx.x; e < 4096; e += 256) {
    const int i = e >> 6, j = e & 63;
    s[i][j] = R[(size_t)(i0 + i) * kL + (j0 + j)];
  }
  __syncthreads();
  for (int dd = threadIdx.x; dd < 127; dd += 256) {
    const int d = dd - 63;
    const int ilo = d < 0 ? 0 : d;
    const int ihi = d < 0 ? 63 + d : 63;
    float sum = 0.f;
    for (int i = ilo; i <= ihi; ++i) sum += s[i][i - d];
    const int tau = (i0 - j0 + d + 2 * kL) & kLMask;
    atomicAdd(&csig[b * kL + tau], sum);
  }
  for (int ss = threadIdx.x; ss < 127; ss += 256) {
    const int ilo = ss < 64 ? 0 : ss - 63;
    const int ihi = ss < 64 ? ss : 63;
    float sum = 0.f;
    for (int i = ilo; i <= ihi; ++i) sum += s[i][ss - i];
    const int tau = (i0 + j0 + ss) & kLMask;
    atomicAdd(&wsig[b * kL + tau], sum);
  }
}

// cosine DFT of (c+w)/2 and (c-w)/2, tau-chunked with atomic accumulation
__global__ __launch_bounds__(256)
void dft_kernel(const float* __restrict__ csig, const float* __restrict__ wsig,
                float* __restrict__ Asp, float* __restrict__ Bsp) {
  __shared__ float ct[kL];
  __shared__ float cp[256];
  __shared__ float cm[256];
  const int b = blockIdx.z;
  const int t0 = blockIdx.y * 256;
  const int f = blockIdx.x * 256 + threadIdx.x;
  for (int e = threadIdx.x; e < kL; e += 256)
    ct[e] = cosf((float)e * (6.283185307179586f / 2048.0f));
  {
    const int e = threadIdx.x;
    const float cv = csig[b * kL + t0 + e];
    const float wv = wsig[b * kL + t0 + e];
    cp[e] = 0.5f * (cv + wv);
    cm[e] = 0.5f * (cv - wv);
  }
  __syncthreads();
  if (f <= kL / 2) {
    float a = 0.f, bb = 0.f;
    for (int t = 0; t < 256; ++t) {
      const float w = ct[(f * (t0 + t)) & kLMask];
      a += cp[t] * w;
      bb += cm[t] * w;
    }
    atomicAdd(&Asp[b * 1025 + f], a);
    atomicAdd(&Bsp[b * 1025 + f], bb);
  }
}

// mean_value[b][tau] = irfft(A - iB)(tau)/512, freq-chunked
__global__ __launch_bounds__(256)
void imean_kernel(const float* __restrict__ Asp, const float* __restrict__ Bsp,
                  float* __restrict__ meanv) {
  __shared__ float sA[256];
  __shared__ float sB[256];
  __shared__ float ct[kL];
  __shared__ float st[kL];
  const int b = blockIdx.z;
  const int f0 = blockIdx.y * 256;
  const int tau = blockIdx.x * 256 + threadIdx.x;
  for (int e = threadIdx.x; e < kL; e += 256) {
    float sv, cv;
    __sincosf((float)e * (6.283185307179586f / 2048.0f), &sv, &cv);
    ct[e] = cv;
    st[e] = sv;
  }
  {
    const int e = threadIdx.x;
    sA[e] = Asp[b * 1025 + f0 + e];
    sB[e] = Bsp[b * 1025 + f0 + e];
  }
  __syncthreads();
  float sum = 0.f;
  const int fstart = (f0 == 0) ? 1 : 0;
  for (int ff = fstart; ff < 256; ++ff) {
    const int r = ((f0 + ff) * tau) & kLMask;
    sum += 2.f * (sA[ff] * ct[r] + sB[ff] * st[r]);
  }
  if (f0 == 0) sum += sA[0];
  if (f0 == 768) {
    const float nyq = Asp[b * 1025 + 1024];
    sum += (tau & 1) ? -nyq : nyq;
  }
  atomicAdd(&meanv[b * kL + tau], sum * (1.0f / 1048576.0f));
}

// top-15 (desc, ties -> lower index) + softmax
__global__ __launch_bounds__(256)
void topk_kernel(const float* __restrict__ meanv, float* __restrict__ wts,
                 int* __restrict__ dly) {
  __shared__ float f[kL];
  __shared__ float rv[256];
  __shared__ int ri[256];
  __shared__ float topv[kTopk];
  __shared__ int topi[kTopk];
  const int b = blockIdx.x;
  const int t = threadIdx.x;
  for (int e = t; e < kL; e += 256) f[e] = meanv[b * kL + e];
  __syncthreads();
  for (int round = 0; round < kTopk; ++round) {
    float bv = -INFINITY;
    int bi = 1 << 30;
    for (int e = t; e < kL; e += 256) {
      const float v = f[e];
      if (v > bv || (v == bv && e < bi)) { bv = v; bi = e; }
    }
    rv[t] = bv; ri[t] = bi;
    __syncthreads();
    for (int s = 128; s > 0; s >>= 1) {
      if (t < s) {
        const float v2 = rv[t + s];
        const int i2 = ri[t + s];
        if (v2 > rv[t] || (v2 == rv[t] && i2 < ri[t])) { rv[t] = v2; ri[t] = i2; }
      }
      __syncthreads();
    }
    if (t == 0) {
      topv[round] = rv[0];
      topi[round] = ri[0];
      f[ri[0]] = -INFINITY;
    }
    __syncthreads();
  }
  if (t == 0) {
    const float m = topv[0];
    float sum = 0.f;
    float e[kTopk];
    for (int i = 0; i < kTopk; ++i) { e[i] = expf(topv[i] - m); sum += e[i]; }
    for (int i = 0; i < kTopk; ++i) {
      wts[b * 16 + i] = e[i] / sum;
      dly[b * 16 + i] = topi[i];
    }
  }
}

// attn_in[b,l,c] = sum_t w_t * v[b,(l+delay_t)%L,c]   (bf16 in/out)
__global__ __launch_bounds__(256)
void agg_kernel(const u16* __restrict__ v, const float* __restrict__ wts,
                const int* __restrict__ dly, u16* __restrict__ out) {
  __shared__ float w[16];
  __shared__ int dl[16];
  const int l = blockIdx.x;
  const int b = blockIdx.y;
  if (threadIdx.x < kTopk) {
    w[threadIdx.x] = wts[b * 16 + threadIdx.x];
    dl[threadIdx.x] = dly[b * 16 + threadIdx.x];
  }
  __syncthreads();
  const u16* vb = v + (size_t)b * kL * kD;
  const int c0 = threadIdx.x;
  const int c1 = threadIdx.x + 256;
  float a0 = 0.f, a1 = 0.f;
  for (int t = 0; t < kTopk; ++t) {
    const int row = (l + dl[t]) & kLMask;
    const u16* vr = vb + (size_t)row * kD;
    a0 += w[t] * b2f(vr[c0]);
    a1 += w[t] * b2f(vr[c1]);
  }
  u16* o = out + ((size_t)b * kL + l) * kD;
  o[c0] = f2b(a0);
  o[c1] = f2b(a1);
}

// out = x - centered 25-tap clamped moving average; optional bf16 copy
__global__ __launch_bounds__(256)
void decomp_kernel(const float* __restrict__ X, float* __restrict__ OutF,
                   u16* __restrict__ OutB, int total) {
  const int idx = blockIdx.x * 256 + threadIdx.x;
  if (idx >= total) return;
  const int c = idx & (kD - 1);
  const int l = (idx / kD) & kLMask;
  const int b = idx / (kD * kL);
  const float* base = X + (size_t)b * kL * kD + c;
  float s = 0.f;
#pragma unroll
  for (int m = -12; m <= 12; ++m) {
    int lm = l + m;
    lm = lm < 0 ? 0 : (lm > kL - 1 ? kL - 1 : lm);
    s += base[(size_t)lm * kD];
  }
  const float v = X[idx] - s * (1.0f / 25.0f);
  OutF[idx] = v;
  if (OutB) OutB[idx] = f2b(v);
}

extern "C" void kernel_launch(void* const* d_in, const int* in_sizes, int n_in,
                              void* d_out, int out_size, void* d_ws, size_t ws_size,
                              hipStream_t stream) {
  const float* x  = (const float*)d_in[0];
  const float* Wq = (const float*)d_in[1];
  const float* bq = (const float*)d_in[2];
  const float* Wk = (const float*)d_in[3];
  const float* bk = (const float*)d_in[4];
  const float* Wv = (const float*)d_in[5];
  const float* bv = (const float*)d_in[6];
  const float* Wo = (const float*)d_in[7];
  const float* bo = (const float*)d_in[8];
  const float* W1 = (const float*)d_in[9];
  const float* W2 = (const float*)d_in[10];
  float* out = (float*)d_out;

  const size_t MiB = 1u << 20;
  const size_t NBLD = (size_t)kB * kL * kD;  // 8,388,608
  const size_t LD = (size_t)kL * kD;         // 1,048,576
  char* base = (char*)d_ws;
  u16*   xb   = (u16*)(base + 0);          // [0,16) ; aggb later
  u16*   qb   = (u16*)(base + 16 * MiB);   // [16,32)
  u16*   kb   = (u16*)(base + 32 * MiB);   // [32,48)
  u16*   vb   = (u16*)(base + 48 * MiB);   // [48,64)
  float* xr   = (float*)(base + 64 * MiB); // [64,96)
  float* s1   = (float*)(base + 96 * MiB); // [96,128)
  u16*   s1b  = (u16*)(base + 128 * MiB);  // [128,144)
  float* s2p  = (float*)(base + 144 * MiB);// [144,176)
  float* gram = (float*)(base + 64 * MiB); // [64,128) during corr phase
  u16*   midb = (u16*)(base + 16 * MiB);   // [16,80)  during FFN
  u16*   aggb = (u16*)(base + 0);          // [0,16)   after QKV
  u16*   Wqt  = (u16*)(base + 176 * MiB);
  u16*   Wkt  = Wqt + 512 * 512;
  u16*   Wvt  = Wkt + 512 * 512;
  u16*   Wot  = Wvt + 512 * 512;
  u16*   W1t  = Wot + 512 * 512;           // [2048][512]
  u16*   W2t  = W1t + (size_t)2048 * 512;  // [512][2048]
  float* csig = (float*)(base + 182 * MiB);
  float* wsig = csig + kB * kL;
  float* Asp  = wsig + kB * kL;
  float* Bsp  = Asp + kB * 1025;
  float* wtsf = Bsp + kB * 1025;
  int*   dlyi = (int*)(wtsf + kB * 16);
  float* meanv = (float*)(dlyi + kB * 16);

  const dim3 blk(256);

  // casts
  cast_f2b_kernel<<<(int)(NBLD / 1024), blk, 0, stream>>>(x, xb);
  transpose_cast_kernel<<<dim3(16, 16), blk, 0, stream>>>(Wq, Wqt, 512, 512);
  transpose_cast_kernel<<<dim3(16, 16), blk, 0, stream>>>(Wk, Wkt, 512, 512);
  transpose_cast_kernel<<<dim3(16, 16), blk, 0, stream>>>(Wv, Wvt, 512, 512);
  transpose_cast_kernel<<<dim3(16, 16), blk, 0, stream>>>(Wo, Wot, 512, 512);
  transpose_cast_kernel<<<dim3(64, 16), blk, 0, stream>>>(W1, W1t, 512, 2048);
  transpose_cast_kernel<<<dim3(16, 64), blk, 0, stream>>>(W2, W2t, 2048, 512);

  // QKV projections (bf16 out)
  mfma_gemm<0, 0, 1><<<dim3(4, 128), blk, 0, stream>>>(
      xb, Wqt, bq, nullptr, nullptr, qb, 16384, 512, 512, 0, 0, 0);
  mfma_gemm<0, 0, 1><<<dim3(4, 128), blk, 0, stream>>>(
      xb, Wkt, bk, nullptr, nullptr, kb, 16384, 512, 512, 0, 0, 0);
  mfma_gemm<0, 0, 1><<<dim3(4, 128), blk, 0, stream>>>(
      xb, Wvt, bv, nullptr, nullptr, vb, 16384, 512, 512, 0, 0, 0);

  // correlation signals: batched Gram (4 at a time) + diag reduce
  hipMemsetAsync(csig, 0, 2 * kB * kL * sizeof(float), stream);
  for (int g = 0; g < 2; ++g) {
    mfma_gemm<0, 1, 0><<<dim3(16, 16, 4), blk, 0, stream>>>(
        qb + (size_t)g * 4 * LD, kb + (size_t)g * 4 * LD, nullptr, nullptr,
        gram, nullptr, kL, kL, kD, LD, LD, (size_t)kL * kL);
    diag_reduce_kernel<<<dim3(32, 32, 4), blk, 0, stream>>>(gram, csig, wsig, g * 4);
  }
  hipMemsetAsync(Asp, 0, 2 * kB * 1025 * sizeof(float), stream);
  dft_kernel<<<dim3(5, 8, 8), blk, 0, stream>>>(csig, wsig, Asp, Bsp);
  hipMemsetAsync(meanv, 0, kB * kL * sizeof(float), stream);
  imean_kernel<<<dim3(8, 4, 8), blk, 0, stream>>>(Asp, Bsp, meanv);
  topk_kernel<<<kB, blk, 0, stream>>>(meanv, wtsf, dlyi);

  // delay aggregation -> bf16, then Wo + bias + residual(x) -> fp32 xr
  agg_kernel<<<dim3(kL, kB), blk, 0, stream>>>(vb, wtsf, dlyi, aggb);
  mfma_gemm<0, 1, 0><<<dim3(4, 128), blk, 0, stream>>>(
      aggb, Wot, bo, x, xr, nullptr, 16384, 512, 512, 0, 0, 0);

  // decomp 1: s1 = xr - trend(xr), dual fp32 + bf16
  decomp_kernel<<<(int)(NBLD / 256), blk, 0, stream>>>(xr, s1, s1b, (int)NBLD);

  // FFN: mid = relu(s1b @ W1) (bf16) ; s2pre = mid @ W2 + s1 (fp32)
  mfma_gemm<1, 0, 1><<<dim3(16, 128), blk, 0, stream>>>(
      s1b, W1t, nullptr, nullptr, nullptr, midb, 16384, 2048, 512, 0, 0, 0);
  mfma_gemm<0, 1, 0><<<dim3(4, 128), blk, 0, stream>>>(
      midb, W2t, nullptr, s1, s2p, nullptr, 16384, 512, 2048, 0, 0, 0);

  // decomp 2 -> output
  decomp_kernel<<<(int)(NBLD / 256), blk, 0, stream>>>(s2p, out, nullptr, (int)NBLD);
}

// Round 3
// 565.030 us; speedup vs baseline: 5.8787x; 1.2137x over previous
//
#include <hip/hip_runtime.h>
#include <math.h>

namespace {
constexpr int kB = 8;
constexpr int kL = 2048;
constexpr int kD = 512;
constexpr int kTopk = 15;
constexpr int kLMask = 2047;
}

typedef unsigned short u16;
using f32x4 = __attribute__((ext_vector_type(4))) float;
using bf16x8 = __attribute__((ext_vector_type(8))) __bf16;

__device__ __forceinline__ u16 f2b(float f) {
  unsigned u = __float_as_uint(f);
  unsigned r = (u + 0x7fffu + ((u >> 16) & 1u)) >> 16;  // RNE
  return (u16)r;
}
__device__ __forceinline__ float b2f(u16 u) {
  return __uint_as_float(((unsigned)u) << 16);
}

typedef __attribute__((address_space(3))) unsigned int lds_u32;
typedef __attribute__((address_space(1))) const unsigned int glb_u32;
__device__ __forceinline__ void gl2lds16(const void* g, void* l) {
  // async global->LDS, 16B per lane; LDS dest = wave-uniform base + lane*16
  __builtin_amdgcn_global_load_lds((glb_u32*)g, (lds_u32*)l, 16, 0, 0);
}

// ---------------------------------------------------------------------------
// bf16 MFMA GEMM, m97-style: 128x128 tile, BK=32, global_load_lds staging.
// MODE 0: 1-D swizzled grid (XCD = lin%8 owns complete A row-strips); M=16384.
// MODE 1: Gram grid (x=batch, y=bn, z=bm); per-batch offsets hardcoded.
// RES: 0 none, 1 fp32, 2 bf16.
// ---------------------------------------------------------------------------
template <int MODE, int RELU, int OUTF, int OUTB, int RES>
__global__ __launch_bounds__(256)
void mfma_gemm(const u16* __restrict__ A, const u16* __restrict__ Bt,
               const float* __restrict__ bias, const float* __restrict__ ResF,
               const u16* __restrict__ ResB, float* __restrict__ outF,
               u16* __restrict__ outB, int N, int K, int lda, int ldb, int nbn) {
  __shared__ u16 As[128 * 32];
  __shared__ u16 Bs[128 * 32];
  int bm, bn;
  size_t aoff = 0, boff = 0, coff = 0;
  if (MODE == 1) {
    const int bt = blockIdx.x;              // batch -> XCD (lin%8 == bx)
    bn = blockIdx.y;
    bm = blockIdx.z;
    aoff = boff = (size_t)bt * kL * 1536;
    coff = (size_t)bt * kL * kL;
  } else {
    const int lin = blockIdx.x;
    const int xcd = lin & 7;
    const int s = lin >> 3;
    const int q = s / nbn;
    bm = xcd * 16 + q;
    bn = s - q * nbn;
  }
  const int tid = threadIdx.x;
  const int wave = tid >> 6;
  const int lane = tid & 63;
  const int ln = lane & 15;
  const int quad = lane >> 4;
  const int wm = (wave >> 1) * 64;
  const int wn = (wave & 1) * 64;
  const int srow = tid >> 2;        // 0..63
  const int scol = (tid & 3) * 8;   // 16B chunk

  const u16* Ab = A + aoff + (size_t)(bm * 128) * lda + scol;
  const u16* Bb = Bt + boff + (size_t)(bn * 128) * ldb + scol;
  char* ldsA = (char*)As + wave * 1024;   // wave-uniform
  char* ldsB = (char*)Bs + wave * 1024;

  f32x4 acc[4][4];
#pragma unroll
  for (int i = 0; i < 4; ++i)
#pragma unroll
    for (int j = 0; j < 4; ++j) acc[i][j] = (f32x4){0.f, 0.f, 0.f, 0.f};

  for (int k0 = 0; k0 < K; k0 += 32) {
    gl2lds16(Ab + (size_t)srow * lda + k0, ldsA);
    gl2lds16(Ab + (size_t)(srow + 64) * lda + k0, ldsA + 4096);
    gl2lds16(Bb + (size_t)srow * ldb + k0, ldsB);
    gl2lds16(Bb + (size_t)(srow + 64) * ldb + k0, ldsB + 4096);
    __syncthreads();
    bf16x8 af[4], bfr[4];
#pragma unroll
    for (int i = 0; i < 4; ++i)
      af[i] = *(const bf16x8*)(As + (wm + i * 16 + ln) * 32 + quad * 8);
#pragma unroll
    for (int j = 0; j < 4; ++j)
      bfr[j] = *(const bf16x8*)(Bs + (wn + j * 16 + ln) * 32 + quad * 8);
#pragma unroll
    for (int i = 0; i < 4; ++i)
#pragma unroll
      for (int j = 0; j < 4; ++j)
        acc[i][j] = __builtin_amdgcn_mfma_f32_16x16x32_bf16(af[i], bfr[j], acc[i][j], 0, 0, 0);
    __syncthreads();
  }

#pragma unroll
  for (int i = 0; i < 4; ++i) {
#pragma unroll
    for (int r = 0; r < 4; ++r) {
      const int row = bm * 128 + wm + i * 16 + quad * 4 + r;
#pragma unroll
      for (int j = 0; j < 4; ++j) {
        const int col = bn * 128 + wn + j * 16 + ln;
        float v = acc[i][j][r];
        if (bias) v += bias[col];
        if (RES == 1) v += ResF[(size_t)row * N + col];
        if (RES == 2) v += b2f(ResB[(size_t)row * N + col]);
        if (RELU) v = fmaxf(v, 0.f);
        if (OUTF) outF[coff + (size_t)row * N + col] = v;
        if (OUTB) outB[coff + (size_t)row * N + col] = f2b(v);
      }
    }
  }
}

__global__ __launch_bounds__(256)
void cast_f2b_kernel(const float* __restrict__ X, u16* __restrict__ Y) {
  const int i = (blockIdx.x * 256 + threadIdx.x) * 4;
  float4 v = *(const float4*)(X + i);
  ushort4 o;
  o.x = f2b(v.x); o.y = f2b(v.y); o.z = f2b(v.z); o.w = f2b(v.w);
  *(ushort4*)(Y + i) = o;
}

// W[K][N] (fp32) -> Wt[N][K] (bf16)
__global__ __launch_bounds__(256)
void transpose_cast_kernel(const float* __restrict__ W, u16* __restrict__ Wt,
                           int K, int N) {
  __shared__ float t[32][33];
  const int k0 = blockIdx.y * 32, n0 = blockIdx.x * 32;
  const int tx = threadIdx.x & 31, ty = threadIdx.x >> 5;
  for (int r = ty; r < 32; r += 8)
    t[r][tx] = W[(size_t)(k0 + r) * N + n0 + tx];
  __syncthreads();
  for (int r = ty; r < 32; r += 8)
    Wt[(size_t)(n0 + r) * K + k0 + tx] = f2b(t[tx][r]);
}

__global__ void concat_bias_kernel(const float* __restrict__ bq,
                                   const float* __restrict__ bk,
                                   const float* __restrict__ bv,
                                   float* __restrict__ o) {
  const int i = blockIdx.x * 256 + threadIdx.x;  // 0..1535
  const float* s = i < 512 ? bq : (i < 1024 ? bk : bv);
  o[i] = s[i & 511];
}

// Diagonal/anti-diagonal sums of bf16 Gram tiles (grid 32,32,8)
__global__ __launch_bounds__(256)
void diag_reduce_kernel(const u16* __restrict__ Rbase, float* __restrict__ csig,
                        float* __restrict__ wsig) {
  __shared__ float s[64][65];
  const u16* R = Rbase + (size_t)blockIdx.z * kL * kL;
  const int b = blockIdx.z;
  const int i0 = blockIdx.y * 64;
  const int j0 = blockIdx.x * 64;
  const int t = threadIdx.x;
#pragma unroll
  for (int pass = 0; pass < 4; ++pass) {
    const int i = pass * 16 + (t >> 4);
    const int j = (t & 15) * 4;
    ushort4 v = *(const ushort4*)(R + (size_t)(i0 + i) * kL + j0 + j);
    s[i][j + 0] = b2f(v.x); s[i][j + 1] = b2f(v.y);
    s[i][j + 2] = b2f(v.z); s[i][j + 3] = b2f(v.w);
  }
  __syncthreads();
  for (int dd = t; dd < 127; dd += 256) {
    const int d = dd - 63;
    const int ilo = d < 0 ? 0 : d;
    const int ihi = d < 0 ? 63 + d : 63;
    float sum = 0.f;
    for (int i = ilo; i <= ihi; ++i) sum += s[i][i - d];
    const int tau = (i0 - j0 + d + 2 * kL) & kLMask;
    atomicAdd(&csig[b * kL + tau], sum);
  }
  for (int ss = t; ss < 127; ss += 256) {
    const int ilo = ss < 64 ? 0 : ss - 63;
    const int ihi = ss < 64 ? ss : 63;
    float sum = 0.f;
    for (int i = ilo; i <= ihi; ++i) sum += s[i][ss - i];
    const int tau = (i0 + j0 + ss) & kLMask;
    atomicAdd(&wsig[b * kL + tau], sum);
  }
}

// meanv(tau) = [ 0.5*(cp(tau)+cp(-tau)) + (1/L) sum_t cm(t)*(G(tau+t)+G(tau-t)) ] / 512
// with cp=(c+w)/2, cm=(c-w)/2, G(u)=cot(pi u/L) for odd u else 0.
__global__ __launch_bounds__(256)
void meanv_kernel(const float* __restrict__ csig, const float* __restrict__ wsig,
                  float* __restrict__ meanv) {
  __shared__ float cp[kL];
  __shared__ float cm[kL];
  __shared__ float G[kL];
  const int b = blockIdx.y;
  const int tau = blockIdx.x * 256 + threadIdx.x;
  for (int e = threadIdx.x; e < kL; e += 256) {
    const float c = csig[b * kL + e];
    const float w = wsig[b * kL + e];
    cp[e] = 0.5f * (c + w);
    cm[e] = 0.5f * (c - w);
    if (e & 1) {
      float sv, cv;
      __sincosf((float)e * (3.14159265358979323846f / 2048.0f), &sv, &cv);
      G[e] = cv / sv;
    } else {
      G[e] = 0.f;
    }
  }
  __syncthreads();
  float S = 0.f;
  for (int t = 0; t < kL; ++t)
    S += cm[t] * (G[(tau + t) & kLMask] + G[(tau - t) & kLMask]);
  const float mv = 0.5f * (cp[tau] + cp[(kL - tau) & kLMask]) + S * (1.0f / 2048.0f);
  meanv[b * kL + tau] = mv * (1.0f / 512.0f);
}

// top-15 (desc, ties -> lower index) + softmax
__global__ __launch_bounds__(256)
void topk_kernel(const float* __restrict__ meanv, float* __restrict__ wts,
                 int* __restrict__ dly) {
  __shared__ float f[kL];
  __shared__ float rv[256];
  __shared__ int ri[256];
  __shared__ float topv[kTopk];
  __shared__ int topi[kTopk];
  const int b = blockIdx.x;
  const int t = threadIdx.x;
  for (int e = t; e < kL; e += 256) f[e] = meanv[b * kL + e];
  __syncthreads();
  for (int round = 0; round < kTopk; ++round) {
    float bv = -INFINITY;
    int bi = 1 << 30;
    for (int e = t; e < kL; e += 256) {
      const float v = f[e];
      if (v > bv || (v == bv && e < bi)) { bv = v; bi = e; }
    }
    rv[t] = bv; ri[t] = bi;
    __syncthreads();
    for (int s = 128; s > 0; s >>= 1) {
      if (t < s) {
        const float v2 = rv[t + s];
        const int i2 = ri[t + s];
        if (v2 > rv[t] || (v2 == rv[t] && i2 < ri[t])) { rv[t] = v2; ri[t] = i2; }
      }
      __syncthreads();
    }
    if (t == 0) {
      topv[round] = rv[0];
      topi[round] = ri[0];
      f[ri[0]] = -INFINITY;
    }
    __syncthreads();
  }
  if (t == 0) {
    const float m = topv[0];
    float sum = 0.f;
    float e[kTopk];
    for (int i = 0; i < kTopk; ++i) { e[i] = expf(topv[i] - m); sum += e[i]; }
    for (int i = 0; i < kTopk; ++i) {
      wts[b * 16 + i] = e[i] / sum;
      dly[b * 16 + i] = topi[i];
    }
  }
}

// attn_in[b,l,c] = sum_t w_t * v[b,(l+delay_t)%L,c]; v strided inside qkv rows
__global__ __launch_bounds__(256)
void agg_kernel(const u16* __restrict__ qkv, const float* __restrict__ wts,
                const int* __restrict__ dly, u16* __restrict__ out) {
  __shared__ float w[16];
  __shared__ int dl[16];
  const int b = blockIdx.y;
  if (threadIdx.x < kTopk) {
    w[threadIdx.x] = wts[b * 16 + threadIdx.x];
    dl[threadIdx.x] = dly[b * 16 + threadIdx.x];
  }
  __syncthreads();
  const int l = blockIdx.x * 4 + (threadIdx.x >> 6);
  const int co = (threadIdx.x & 63) * 8;
  const u16* vb = qkv + (size_t)b * kL * 1536 + 1024 + co;
  float a[8] = {0.f, 0.f, 0.f, 0.f, 0.f, 0.f, 0.f, 0.f};
  for (int t = 0; t < kTopk; ++t) {
    const int row = (l + dl[t]) & kLMask;
    float4 rv = *(const float4*)(vb + (size_t)row * 1536);
    const u16* p = (const u16*)&rv;
    const float wt = w[t];
#pragma unroll
    for (int e = 0; e < 8; ++e) a[e] += wt * b2f(p[e]);
  }
  u16 ob[8];
#pragma unroll
  for (int e = 0; e < 8; ++e) ob[e] = f2b(a[e]);
  *(float4*)(out + ((size_t)b * kL + l) * kD + co) = *(const float4*)ob;
}

// streaming 25-tap clamped moving-average decomp; out = x - trend
template <int OUTF, int OUTB>
__global__ __launch_bounds__(256)
void decomp_stream(const float* __restrict__ X, float* __restrict__ OF,
                   u16* __restrict__ OB) {
  const int c = blockIdx.x * 256 + threadIdx.x;  // 0..511
  const int b = blockIdx.y;
  const int l0 = blockIdx.z * 64;
  const float* base = X + (size_t)b * kL * kD + c;
  float sum = 0.f;
#pragma unroll
  for (int m = -12; m <= 12; ++m) {
    int lm = l0 + m;
    lm = lm < 0 ? 0 : (lm > kL - 1 ? kL - 1 : lm);
    sum += base[(size_t)lm * kD];
  }
#pragma unroll 4
  for (int l = l0; l < l0 + 64; ++l) {
    const float val = base[(size_t)l * kD];
    const float o = val - sum * (1.0f / 25.0f);
    const size_t idx = ((size_t)b * kL + l) * kD + c;
    if (OUTF) OF[idx] = o;
    if (OUTB) OB[idx] = f2b(o);
    const int la = l + 13 > kL - 1 ? kL - 1 : l + 13;
    const int lr = l - 12 < 0 ? 0 : l - 12;
    sum += base[(size_t)la * kD] - base[(size_t)lr * kD];
  }
}

extern "C" void kernel_launch(void* const* d_in, const int* in_sizes, int n_in,
                              void* d_out, int out_size, void* d_ws, size_t ws_size,
                              hipStream_t stream) {
  const float* x  = (const float*)d_in[0];
  const float* Wq = (const float*)d_in[1];
  const float* bq = (const float*)d_in[2];
  const float* Wk = (const float*)d_in[3];
  const float* bk = (const float*)d_in[4];
  const float* Wv = (const float*)d_in[5];
  const float* bv = (const float*)d_in[6];
  const float* Wo = (const float*)d_in[7];
  const float* bo = (const float*)d_in[8];
  const float* W1 = (const float*)d_in[9];
  const float* W2 = (const float*)d_in[10];
  float* out = (float*)d_out;

  const size_t MiB = 1u << 20;
  const size_t NBLD = (size_t)kB * kL * kD;  // 8,388,608
  char* base = (char*)d_ws;
  u16*   qkvb  = (u16*)(base);               // [0,48) MiB
  u16*   gramb = (u16*)(base + 48 * MiB);    // [48,112) ; midb later
  u16*   midb  = gramb;
  u16*   xb    = (u16*)(base + 112 * MiB);   // [112,128) ; aggb later
  u16*   aggb  = xb;
  float* xr    = (float*)(base + 128 * MiB); // [128,160) ; s2p later
  float* s2p   = xr;
  u16*   s1b   = (u16*)(base + 160 * MiB);   // [160,176)
  u16*   Wqkvt = (u16*)(base + 176 * MiB);   // 1.5 MiB
  u16*   Wot   = (u16*)(base + 178 * MiB);   // 0.5 MiB
  u16*   W1t   = (u16*)(base + 179 * MiB);   // 2 MiB
  u16*   W2t   = (u16*)(base + 181 * MiB);   // 2 MiB
  float* bqkv  = (float*)(base + 183 * MiB);
  float* csig  = bqkv + 2048;
  float* wsig  = csig + kB * kL;
  float* meanv = wsig + kB * kL;
  float* wtsf  = meanv + kB * kL;
  int*   dlyi  = (int*)(wtsf + kB * 16);

  const dim3 blk(256);

  // casts / weight prep
  cast_f2b_kernel<<<(int)(NBLD / 1024), blk, 0, stream>>>(x, xb);
  transpose_cast_kernel<<<dim3(16, 16), blk, 0, stream>>>(Wq, Wqkvt, 512, 512);
  transpose_cast_kernel<<<dim3(16, 16), blk, 0, stream>>>(Wk, Wqkvt + 512 * 512, 512, 512);
  transpose_cast_kernel<<<dim3(16, 16), blk, 0, stream>>>(Wv, Wqkvt + 1024 * 512, 512, 512);
  transpose_cast_kernel<<<dim3(16, 16), blk, 0, stream>>>(Wo, Wot, 512, 512);
  transpose_cast_kernel<<<dim3(64, 16), blk, 0, stream>>>(W1, W1t, 512, 2048);
  transpose_cast_kernel<<<dim3(16, 64), blk, 0, stream>>>(W2, W2t, 2048, 512);
  concat_bias_kernel<<<dim3(6), blk, 0, stream>>>(bq, bk, bv, bqkv);
  hipMemsetAsync(csig, 0, 2 * kB * kL * sizeof(float), stream);

  // fused QKV projection: [16384,512] @ [1536,512]^T -> qkvb bf16
  mfma_gemm<0, 0, 0, 1, 0><<<dim3(1536), blk, 0, stream>>>(
      xb, Wqkvt, bqkv, nullptr, nullptr, nullptr, qkvb, 1536, 512, 512, 512, 12);

  // per-batch Gram q@k^T -> bf16 (one batch per XCD)
  mfma_gemm<1, 0, 0, 1, 0><<<dim3(8, 16, 16), blk, 0, stream>>>(
      qkvb, qkvb + 512, nullptr, nullptr, nullptr, nullptr, gramb,
      2048, 512, 1536, 1536, 0);
  diag_reduce_kernel<<<dim3(32, 32, 8), blk, 0, stream>>>(gramb, csig, wsig);

  meanv_kernel<<<dim3(8, 8), blk, 0, stream>>>(csig, wsig, meanv);
  topk_kernel<<<kB, blk, 0, stream>>>(meanv, wtsf, dlyi);

  // delay aggregation -> aggb bf16 ; Wo + bias + residual(x) -> xr fp32
  agg_kernel<<<dim3(512, 8), blk, 0, stream>>>(qkvb, wtsf, dlyi, aggb);
  mfma_gemm<0, 0, 1, 0, 1><<<dim3(512), blk, 0, stream>>>(
      aggb, Wot, bo, x, nullptr, xr, nullptr, 512, 512, 512, 512, 4);

  // decomp 1 -> s1b bf16
  decomp_stream<0, 1><<<dim3(2, 8, 32), blk, 0, stream>>>(xr, nullptr, s1b);

  // FFN1: relu(s1b @ W1) -> midb bf16
  mfma_gemm<0, 1, 0, 1, 0><<<dim3(2048), blk, 0, stream>>>(
      s1b, W1t, nullptr, nullptr, nullptr, nullptr, midb, 2048, 512, 512, 512, 16);
  // FFN2: midb @ W2 + s1b -> s2p fp32
  mfma_gemm<0, 0, 1, 0, 2><<<dim3(512), blk, 0, stream>>>(
      midb, W2t, nullptr, nullptr, s1b, s2p, nullptr, 512, 2048, 2048, 2048, 4);

  // decomp 2 -> out fp32
  decomp_stream<1, 0><<<dim3(2, 8, 32), blk, 0, stream>>>(s2p, out, nullptr);
}

// Round 4
// 554.979 us; speedup vs baseline: 5.9852x; 1.0181x over previous
//
#include <hip/hip_runtime.h>
#include <math.h>

namespace {
constexpr int kB = 8;
constexpr int kL = 2048;
constexpr int kD = 512;
constexpr int kTopk = 15;
constexpr int kLMask = 2047;
}

typedef unsigned short u16;
using f32x4 = __attribute__((ext_vector_type(4))) float;
using bf16x8 = __attribute__((ext_vector_type(8))) __bf16;

__device__ __forceinline__ u16 f2b(float f) {
  unsigned u = __float_as_uint(f);
  unsigned r = (u + 0x7fffu + ((u >> 16) & 1u)) >> 16;  // RNE
  return (u16)r;
}
__device__ __forceinline__ float b2f(u16 u) {
  return __uint_as_float(((unsigned)u) << 16);
}

typedef __attribute__((address_space(3))) unsigned int lds_u32;
typedef __attribute__((address_space(1))) const unsigned int glb_u32;
__device__ __forceinline__ void gl2lds16(const void* g, void* l) {
  __builtin_amdgcn_global_load_lds((glb_u32*)g, (lds_u32*)l, 16, 0, 0);
}

// ---------------------------------------------------------------------------
// bf16 MFMA GEMM, m97-style: 128x128 tile, BK=32, global_load_lds staging.
// 1-D swizzled grid: XCD = lin%8 owns complete A row-strips (M=16384 fixed).
// SPLIT: grid doubled; split = lin>>9 takes K-half, writes to out + split*M*N.
// RES: 0 none, 1 fp32 (always), 2 bf16 (split 0 only).
// ---------------------------------------------------------------------------
template <int SPLIT, int RELU, int OUTF, int OUTB, int RES>
__global__ __launch_bounds__(256)
void mfma_gemm(const u16* __restrict__ A, const u16* __restrict__ Bt,
               const float* __restrict__ bias, const float* __restrict__ ResF,
               const u16* __restrict__ ResB, float* __restrict__ outF,
               u16* __restrict__ outB, int N, int K, int lda, int ldb, int nbn) {
  __shared__ u16 As[128 * 32];
  __shared__ u16 Bs[128 * 32];
  int lin = blockIdx.x;
  int split = 0;
  if (SPLIT) { split = lin >> 9; lin &= 511; }
  const int xcd = lin & 7;
  const int s = lin >> 3;
  const int q = s / nbn;
  const int bm = xcd * 16 + q;
  const int bn = s - q * nbn;
  const int tid = threadIdx.x;
  const int wave = tid >> 6;
  const int lane = tid & 63;
  const int ln = lane & 15;
  const int quad = lane >> 4;
  const int wm = (wave >> 1) * 64;
  const int wn = (wave & 1) * 64;
  const int srow = tid >> 2;
  const int scol = (tid & 3) * 8;

  const size_t koff = (size_t)split * K;
  const u16* Ab = A + koff + (size_t)(bm * 128) * lda + scol;
  const u16* Bb = Bt + koff + (size_t)(bn * 128) * ldb + scol;
  char* ldsA = (char*)As + wave * 1024;
  char* ldsB = (char*)Bs + wave * 1024;

  f32x4 acc[4][4];
#pragma unroll
  for (int i = 0; i < 4; ++i)
#pragma unroll
    for (int j = 0; j < 4; ++j) acc[i][j] = (f32x4){0.f, 0.f, 0.f, 0.f};

  for (int k0 = 0; k0 < K; k0 += 32) {
    gl2lds16(Ab + (size_t)srow * lda + k0, ldsA);
    gl2lds16(Ab + (size_t)(srow + 64) * lda + k0, ldsA + 4096);
    gl2lds16(Bb + (size_t)srow * ldb + k0, ldsB);
    gl2lds16(Bb + (size_t)(srow + 64) * ldb + k0, ldsB + 4096);
    __syncthreads();
    bf16x8 af[4], bfr[4];
#pragma unroll
    for (int i = 0; i < 4; ++i)
      af[i] = *(const bf16x8*)(As + (wm + i * 16 + ln) * 32 + quad * 8);
#pragma unroll
    for (int j = 0; j < 4; ++j)
      bfr[j] = *(const bf16x8*)(Bs + (wn + j * 16 + ln) * 32 + quad * 8);
#pragma unroll
    for (int i = 0; i < 4; ++i)
#pragma unroll
      for (int j = 0; j < 4; ++j)
        acc[i][j] = __builtin_amdgcn_mfma_f32_16x16x32_bf16(af[i], bfr[j], acc[i][j], 0, 0, 0);
    __syncthreads();
  }

  const size_t cbase = (size_t)split * ((size_t)16384 * N);
  const bool res2 = (RES == 2) && (!SPLIT || split == 0);
#pragma unroll
  for (int i = 0; i < 4; ++i) {
#pragma unroll
    for (int r = 0; r < 4; ++r) {
      const int row = bm * 128 + wm + i * 16 + quad * 4 + r;
#pragma unroll
      for (int j = 0; j < 4; ++j) {
        const int col = bn * 128 + wn + j * 16 + ln;
        float v = acc[i][j][r];
        if (bias) v += bias[col];
        if (RES == 1) v += ResF[(size_t)row * N + col];
        if (RES == 2) { if (res2) v += b2f(ResB[(size_t)row * N + col]); }
        if (RELU) v = fmaxf(v, 0.f);
        if (OUTF) outF[cbase + (size_t)row * N + col] = v;
        if (OUTB) outB[cbase + (size_t)row * N + col] = f2b(v);
      }
    }
  }
}

// ---------------------------------------------------------------------------
// Per-batch Gram q@k^T with diagonal/anti-diagonal reduction fused in the
// epilogue: no Gram matrix ever touches HBM. Grid (8 batches -> XCD, 16, 16).
// ---------------------------------------------------------------------------
__global__ __launch_bounds__(256)
void gram_diag(const u16* __restrict__ qkv, float* __restrict__ csig,
               float* __restrict__ wsig) {
  __shared__ u16 As[128 * 32];
  __shared__ u16 Bs[128 * 32];
  __shared__ float tile[64][65];
  __shared__ float c_acc[256];
  __shared__ float w_acc[256];
  const int bt = blockIdx.x;
  const int bn = blockIdx.y;
  const int bm = blockIdx.z;
  const int tid = threadIdx.x;
  const int wave = tid >> 6;
  const int lane = tid & 63;
  const int ln = lane & 15;
  const int quad = lane >> 4;
  const int wm = (wave >> 1) * 64;
  const int wn = (wave & 1) * 64;
  const int srow = tid >> 2;
  const int scol = (tid & 3) * 8;

  const u16* Qb = qkv + (size_t)bt * kL * 1536 + (size_t)(bm * 128) * 1536 + scol;
  const u16* Kb = qkv + (size_t)bt * kL * 1536 + 512 + (size_t)(bn * 128) * 1536 + scol;
  char* ldsA = (char*)As + wave * 1024;
  char* ldsB = (char*)Bs + wave * 1024;

  f32x4 acc[4][4];
#pragma unroll
  for (int i = 0; i < 4; ++i)
#pragma unroll
    for (int j = 0; j < 4; ++j) acc[i][j] = (f32x4){0.f, 0.f, 0.f, 0.f};

  for (int k0 = 0; k0 < 512; k0 += 32) {
    gl2lds16(Qb + (size_t)srow * 1536 + k0, ldsA);
    gl2lds16(Qb + (size_t)(srow + 64) * 1536 + k0, ldsA + 4096);
    gl2lds16(Kb + (size_t)srow * 1536 + k0, ldsB);
    gl2lds16(Kb + (size_t)(srow + 64) * 1536 + k0, ldsB + 4096);
    __syncthreads();
    bf16x8 af[4], bfr[4];
#pragma unroll
    for (int i = 0; i < 4; ++i)
      af[i] = *(const bf16x8*)(As + (wm + i * 16 + ln) * 32 + quad * 8);
#pragma unroll
    for (int j = 0; j < 4; ++j)
      bfr[j] = *(const bf16x8*)(Bs + (wn + j * 16 + ln) * 32 + quad * 8);
#pragma unroll
    for (int i = 0; i < 4; ++i)
#pragma unroll
      for (int j = 0; j < 4; ++j)
        acc[i][j] = __builtin_amdgcn_mfma_f32_16x16x32_bf16(af[i], bfr[j], acc[i][j], 0, 0, 0);
    __syncthreads();
  }

  // epilogue: per-quadrant diag sums into block-local partials
  c_acc[tid] = 0.f;
  w_acc[tid] = 0.f;
  __syncthreads();
  for (int qd = 0; qd < 4; ++qd) {
    const int qwm = (qd >> 1) * 64, qwn = (qd & 1) * 64;
    if (wave == qd) {
#pragma unroll
      for (int i = 0; i < 4; ++i)
#pragma unroll
        for (int j = 0; j < 4; ++j)
#pragma unroll
          for (int r = 0; r < 4; ++r)
            tile[i * 16 + quad * 4 + r][j * 16 + ln] = acc[i][j][r];
    }
    __syncthreads();
    if (tid < 127) {
      const int d = tid - 63;
      const int ilo = d < 0 ? 0 : d;
      const int ihi = d < 0 ? 63 + d : 63;
      float sum = 0.f;
      for (int i = ilo; i <= ihi; ++i) sum += tile[i][i - d];
      c_acc[qwm - qwn + d + 127] += sum;
    } else if (tid < 254) {
      const int ss = tid - 127;
      const int ilo = ss < 64 ? 0 : ss - 63;
      const int ihi = ss < 64 ? ss : 63;
      float sum = 0.f;
      for (int i = ilo; i <= ihi; ++i) sum += tile[i][ss - i];
      w_acc[qwm + qwn + ss] += sum;
    }
    __syncthreads();
  }
  if (tid < 255) {
    const int i0 = bm * 128, j0 = bn * 128;
    atomicAdd(&csig[bt * kL + ((i0 - j0 + tid - 127) & kLMask)], c_acc[tid]);
    atomicAdd(&wsig[bt * kL + ((i0 + j0 + tid) & kLMask)], w_acc[tid]);
  }
}

__global__ __launch_bounds__(256)
void cast_f2b_kernel(const float* __restrict__ X, u16* __restrict__ Y) {
  const int i = (blockIdx.x * 256 + threadIdx.x) * 4;
  float4 v = *(const float4*)(X + i);
  ushort4 o;
  o.x = f2b(v.x); o.y = f2b(v.y); o.z = f2b(v.z); o.w = f2b(v.w);
  *(ushort4*)(Y + i) = o;
}

// 4x 512x512 W[K][N] fp32 -> Wt[N][K] bf16, z-batched
__global__ __launch_bounds__(256)
void transpose4_kernel(const float* __restrict__ W0, const float* __restrict__ W1,
                       const float* __restrict__ W2, const float* __restrict__ W3,
                       u16* __restrict__ dst) {
  __shared__ float t[32][33];
  const int z = blockIdx.z;
  const float* W = z == 0 ? W0 : z == 1 ? W1 : z == 2 ? W2 : W3;
  u16* Wt = dst + (size_t)z * 512 * 512;
  const int k0 = blockIdx.y * 32, n0 = blockIdx.x * 32;
  const int tx = threadIdx.x & 31, ty = threadIdx.x >> 5;
  for (int r = ty; r < 32; r += 8)
    t[r][tx] = W[(size_t)(k0 + r) * 512 + n0 + tx];
  __syncthreads();
  for (int r = ty; r < 32; r += 8)
    Wt[(size_t)(n0 + r) * 512 + k0 + tx] = f2b(t[tx][r]);
}

// generic W[K][N] fp32 -> Wt[N][K] bf16
__global__ __launch_bounds__(256)
void transpose_cast_kernel(const float* __restrict__ W, u16* __restrict__ Wt,
                           int K, int N) {
  __shared__ float t[32][33];
  const int k0 = blockIdx.y * 32, n0 = blockIdx.x * 32;
  const int tx = threadIdx.x & 31, ty = threadIdx.x >> 5;
  for (int r = ty; r < 32; r += 8)
    t[r][tx] = W[(size_t)(k0 + r) * N + n0 + tx];
  __syncthreads();
  for (int r = ty; r < 32; r += 8)
    Wt[(size_t)(n0 + r) * K + k0 + tx] = f2b(t[tx][r]);
}

__global__ void concat_bias_kernel(const float* __restrict__ bq,
                                   const float* __restrict__ bk,
                                   const float* __restrict__ bv,
                                   float* __restrict__ o) {
  const int i = blockIdx.x * 256 + threadIdx.x;
  const float* s = i < 512 ? bq : (i < 1024 ? bk : bv);
  o[i] = s[i & 511];
}

// meanv(tau) += [cp-term (z==0) + (1/L) sum_{t in chunk} cm(t)*(G(tau+t)+G(tau-t))]/512
__global__ __launch_bounds__(256)
void meanv_kernel(const float* __restrict__ csig, const float* __restrict__ wsig,
                  float* __restrict__ meanv) {
  __shared__ float cm[512];
  __shared__ float G[kL];
  const int b = blockIdx.y;
  const int z = blockIdx.z;
  const int tau = blockIdx.x * 256 + threadIdx.x;
  for (int e = threadIdx.x; e < kL; e += 256) {
    if (e & 1) {
      float sv, cv;
      __sincosf((float)e * (3.14159265358979323846f / 2048.0f), &sv, &cv);
      G[e] = cv / sv;
    } else {
      G[e] = 0.f;
    }
  }
  for (int e = threadIdx.x; e < 512; e += 256) {
    const int t = z * 512 + e;
    cm[e] = 0.5f * (csig[b * kL + t] - wsig[b * kL + t]);
  }
  __syncthreads();
  float S = 0.f;
  for (int tt = 0; tt < 512; ++tt) {
    const int t = z * 512 + tt;
    S += cm[tt] * (G[(tau + t) & kLMask] + G[(tau - t) & kLMask]);
  }
  float res = S * (1.0f / 2048.0f);
  if (z == 0) {
    const float cpt = 0.5f * (csig[b * kL + tau] + wsig[b * kL + tau]);
    const int mt = (kL - tau) & kLMask;
    const float cpm = 0.5f * (csig[b * kL + mt] + wsig[b * kL + mt]);
    res += 0.5f * (cpt + cpm);
  }
  atomicAdd(&meanv[b * kL + tau], res * (1.0f / 512.0f));
}

// top-15 (desc, ties -> lower index) + softmax
__global__ __launch_bounds__(256)
void topk_kernel(const float* __restrict__ meanv, float* __restrict__ wts,
                 int* __restrict__ dly) {
  __shared__ float f[kL];
  __shared__ float rv[256];
  __shared__ int ri[256];
  __shared__ float topv[kTopk];
  __shared__ int topi[kTopk];
  const int b = blockIdx.x;
  const int t = threadIdx.x;
  for (int e = t; e < kL; e += 256) f[e] = meanv[b * kL + e];
  __syncthreads();
  for (int round = 0; round < kTopk; ++round) {
    float bv = -INFINITY;
    int bi = 1 << 30;
    for (int e = t; e < kL; e += 256) {
      const float v = f[e];
      if (v > bv || (v == bv && e < bi)) { bv = v; bi = e; }
    }
    rv[t] = bv; ri[t] = bi;
    __syncthreads();
    for (int s = 128; s > 0; s >>= 1) {
      if (t < s) {
        const float v2 = rv[t + s];
        const int i2 = ri[t + s];
        if (v2 > rv[t] || (v2 == rv[t] && i2 < ri[t])) { rv[t] = v2; ri[t] = i2; }
      }
      __syncthreads();
    }
    if (t == 0) {
      topv[round] = rv[0];
      topi[round] = ri[0];
      f[ri[0]] = -INFINITY;
    }
    __syncthreads();
  }
  if (t == 0) {
    const float m = topv[0];
    float sum = 0.f;
    float e[kTopk];
    for (int i = 0; i < kTopk; ++i) { e[i] = expf(topv[i] - m); sum += e[i]; }
    for (int i = 0; i < kTopk; ++i) {
      wts[b * 16 + i] = e[i] / sum;
      dly[b * 16 + i] = topi[i];
    }
  }
}

// attn_in[b,l,c] = sum_t w_t * v[b,(l+delay_t)%L,c]
__global__ __launch_bounds__(256)
void agg_kernel(const u16* __restrict__ qkv, const float* __restrict__ wts,
                const int* __restrict__ dly, u16* __restrict__ out) {
  __shared__ float w[16];
  __shared__ int dl[16];
  const int b = blockIdx.y;
  if (threadIdx.x < kTopk) {
    w[threadIdx.x] = wts[b * 16 + threadIdx.x];
    dl[threadIdx.x] = dly[b * 16 + threadIdx.x];
  }
  __syncthreads();
  const int l = blockIdx.x * 4 + (threadIdx.x >> 6);
  const int co = (threadIdx.x & 63) * 8;
  const u16* vb = qkv + (size_t)b * kL * 1536 + 1024 + co;
  float a[8] = {0.f, 0.f, 0.f, 0.f, 0.f, 0.f, 0.f, 0.f};
  for (int t = 0; t < kTopk; ++t) {
    const int row = (l + dl[t]) & kLMask;
    float4 rv = *(const float4*)(vb + (size_t)row * 1536);
    const u16* p = (const u16*)&rv;
    const float wt = w[t];
#pragma unroll
    for (int e = 0; e < 8; ++e) a[e] += wt * b2f(p[e]);
  }
  u16 ob[8];
#pragma unroll
  for (int e = 0; e < 8; ++e) ob[e] = f2b(a[e]);
  *(float4*)(out + ((size_t)b * kL + l) * kD + co) = *(const float4*)ob;
}

// decomp, bf16 in -> bf16 out (streaming 25-tap clamped MA)
__global__ __launch_bounds__(256)
void decomp_b2b(const u16* __restrict__ X, u16* __restrict__ OB) {
  const int c = blockIdx.x * 256 + threadIdx.x;
  const int b = blockIdx.y;
  const int l0 = blockIdx.z * 64;
  const u16* base = X + (size_t)b * kL * kD + c;
  float sum = 0.f;
#pragma unroll
  for (int m = -12; m <= 12; ++m) {
    int lm = l0 + m;
    lm = lm < 0 ? 0 : (lm > kL - 1 ? kL - 1 : lm);
    sum += b2f(base[(size_t)lm * kD]);
  }
#pragma unroll 4
  for (int l = l0; l < l0 + 64; ++l) {
    const float val = b2f(base[(size_t)l * kD]);
    OB[((size_t)b * kL + l) * kD + c] = f2b(val - sum * (1.0f / 25.0f));
    const int la = l + 13 > kL - 1 ? kL - 1 : l + 13;
    const int lr = l - 12 < 0 ? 0 : l - 12;
    sum += b2f(base[(size_t)la * kD]) - b2f(base[(size_t)lr * kD]);
  }
}

// decomp of (X1+X2), fp32 -> fp32 out
__global__ __launch_bounds__(256)
void decomp_ff2(const float* __restrict__ X1, const float* __restrict__ X2,
                float* __restrict__ OF) {
  const int c = blockIdx.x * 256 + threadIdx.x;
  const int b = blockIdx.y;
  const int l0 = blockIdx.z * 64;
  const size_t off = (size_t)b * kL * kD + c;
  const float* b1 = X1 + off;
  const float* b2 = X2 + off;
  float sum = 0.f;
#pragma unroll
  for (int m = -12; m <= 12; ++m) {
    int lm = l0 + m;
    lm = lm < 0 ? 0 : (lm > kL - 1 ? kL - 1 : lm);
    sum += b1[(size_t)lm * kD] + b2[(size_t)lm * kD];
  }
#pragma unroll 4
  for (int l = l0; l < l0 + 64; ++l) {
    const float val = b1[(size_t)l * kD] + b2[(size_t)l * kD];
    OF[((size_t)b * kL + l) * kD + c] = val - sum * (1.0f / 25.0f);
    const int la = l + 13 > kL - 1 ? kL - 1 : l + 13;
    const int lr = l - 12 < 0 ? 0 : l - 12;
    sum += b1[(size_t)la * kD] + b2[(size_t)la * kD]
         - b1[(size_t)lr * kD] - b2[(size_t)lr * kD];
  }
}

extern "C" void kernel_launch(void* const* d_in, const int* in_sizes, int n_in,
                              void* d_out, int out_size, void* d_ws, size_t ws_size,
                              hipStream_t stream) {
  const float* x  = (const float*)d_in[0];
  const float* Wq = (const float*)d_in[1];
  const float* bq = (const float*)d_in[2];
  const float* Wk = (const float*)d_in[3];
  const float* bk = (const float*)d_in[4];
  const float* Wv = (const float*)d_in[5];
  const float* bv = (const float*)d_in[6];
  const float* Wo = (const float*)d_in[7];
  const float* bo = (const float*)d_in[8];
  const float* W1 = (const float*)d_in[9];
  const float* W2 = (const float*)d_in[10];
  float* out = (float*)d_out;

  const size_t MiB = 1u << 20;
  const size_t NBLD = (size_t)kB * kL * kD;  // 8,388,608
  char* base = (char*)d_ws;
  u16*   qkvb  = (u16*)(base);               // [0,48)
  u16*   xb    = (u16*)(base + 48 * MiB);    // [48,64) ; aggb aliases
  u16*   aggb  = xb;
  u16*   xrb   = (u16*)(base + 64 * MiB);    // [64,80)
  u16*   s1b   = (u16*)(base + 80 * MiB);    // [80,96)
  u16*   midb  = (u16*)(base + 96 * MiB);    // [96,160)
  float* s2p   = (float*)(base);             // [0,64) after qkvb/aggb dead
  u16*   Wqkvt = (u16*)(base + 160 * MiB);   // 2 MiB (incl Wot as slot 3)
  u16*   Wot   = Wqkvt + 3 * 512 * 512;
  u16*   W1t   = (u16*)(base + 162 * MiB);   // 2 MiB
  u16*   W2t   = (u16*)(base + 164 * MiB);   // 2 MiB
  float* bqkv  = (float*)(base + 166 * MiB);
  float* csig  = bqkv + 2048;
  float* wsig  = csig + kB * kL;
  float* meanv = wsig + kB * kL;
  float* wtsf  = meanv + kB * kL;
  int*   dlyi  = (int*)(wtsf + kB * 16);

  const dim3 blk(256);

  // input cast + weight prep
  cast_f2b_kernel<<<(int)(NBLD / 1024), blk, 0, stream>>>(x, xb);
  transpose4_kernel<<<dim3(16, 16, 4), blk, 0, stream>>>(Wq, Wk, Wv, Wo, Wqkvt);
  transpose_cast_kernel<<<dim3(64, 16), blk, 0, stream>>>(W1, W1t, 512, 2048);
  transpose_cast_kernel<<<dim3(16, 64), blk, 0, stream>>>(W2, W2t, 2048, 512);
  concat_bias_kernel<<<dim3(6), blk, 0, stream>>>(bq, bk, bv, bqkv);
  hipMemsetAsync(csig, 0, 3 * kB * kL * sizeof(float), stream);  // csig,wsig,meanv

  // fused QKV projection -> qkvb bf16
  mfma_gemm<0, 0, 0, 1, 0><<<dim3(1536), blk, 0, stream>>>(
      xb, Wqkvt, bqkv, nullptr, nullptr, nullptr, qkvb, 1536, 512, 512, 512, 12);

  // Gram + fused diag reduction (no Gram materialization)
  gram_diag<<<dim3(8, 16, 16), blk, 0, stream>>>(qkvb, csig, wsig);

  meanv_kernel<<<dim3(8, 8, 4), blk, 0, stream>>>(csig, wsig, meanv);
  topk_kernel<<<kB, blk, 0, stream>>>(meanv, wtsf, dlyi);

  // delay aggregation -> aggb bf16 ; Wo + bias + residual(x) -> xrb bf16
  agg_kernel<<<dim3(512, 8), blk, 0, stream>>>(qkvb, wtsf, dlyi, aggb);
  mfma_gemm<0, 0, 0, 1, 1><<<dim3(512), blk, 0, stream>>>(
      aggb, Wot, bo, x, nullptr, nullptr, xrb, 512, 512, 512, 512, 4);

  // decomp 1 -> s1b bf16
  decomp_b2b<<<dim3(2, 8, 32), blk, 0, stream>>>(xrb, s1b);

  // FFN1: relu(s1b @ W1) -> midb bf16
  mfma_gemm<0, 1, 0, 1, 0><<<dim3(2048), blk, 0, stream>>>(
      s1b, W1t, nullptr, nullptr, nullptr, nullptr, midb, 2048, 512, 512, 512, 16);
  // FFN2 split-K=2 (one dispatch, 1024 blocks): s2p[0]=K-half0 + s1 residual,
  // s2p[1]=K-half1
  mfma_gemm<1, 0, 1, 0, 2><<<dim3(1024), blk, 0, stream>>>(
      midb, W2t, nullptr, nullptr, s1b, s2p, nullptr, 512, 1024, 2048, 2048, 4);

  // decomp 2 over (partial0 + partial1) -> out fp32
  decomp_ff2<<<dim3(2, 8, 32), blk, 0, stream>>>(s2p, s2p + NBLD, out);
}

// Round 5
// 532.871 us; speedup vs baseline: 6.2335x; 1.0415x over previous
//
#include <hip/hip_runtime.h>
#include <math.h>

namespace {
constexpr int kB = 8;
constexpr int kL = 2048;
constexpr int kD = 512;
constexpr int kTopk = 15;
constexpr int kLMask = 2047;
}

typedef unsigned short u16;
using f32x4 = __attribute__((ext_vector_type(4))) float;
using bf16x8 = __attribute__((ext_vector_type(8))) __bf16;

__device__ __forceinline__ u16 f2b(float f) {
  unsigned u = __float_as_uint(f);
  unsigned r = (u + 0x7fffu + ((u >> 16) & 1u)) >> 16;  // RNE
  return (u16)r;
}
__device__ __forceinline__ float b2f(u16 u) {
  return __uint_as_float(((unsigned)u) << 16);
}

typedef __attribute__((address_space(3))) unsigned int lds_u32;
typedef __attribute__((address_space(1))) const unsigned int glb_u32;
__device__ __forceinline__ void gl2lds16(const void* g, void* l) {
  __builtin_amdgcn_global_load_lds((glb_u32*)g, (lds_u32*)l, 16, 0, 0);
}

// ---------------------------------------------------------------------------
// bf16 MFMA GEMM, m97-style: 128x128 tile, BK=32, global_load_lds staging.
// 1-D swizzled grid: XCD = lin%8 owns complete A row-strips (M=16384 fixed).
// SPLIT: grid doubled; split = lin>>9 takes K-half, writes to out + split*M*N.
// RES: 0 none, 1 fp32 (always), 2 bf16 (split 0 only).
// ---------------------------------------------------------------------------
template <int SPLIT, int RELU, int OUTF, int OUTB, int RES>
__global__ __launch_bounds__(256)
void mfma_gemm(const u16* __restrict__ A, const u16* __restrict__ Bt,
               const float* __restrict__ bias, const float* __restrict__ ResF,
               const u16* __restrict__ ResB, float* __restrict__ outF,
               u16* __restrict__ outB, int N, int K, int lda, int ldb, int nbn) {
  __shared__ u16 As[128 * 32];
  __shared__ u16 Bs[128 * 32];
  int lin = blockIdx.x;
  int split = 0;
  if (SPLIT) { split = lin >> 9; lin &= 511; }
  const int xcd = lin & 7;
  const int s = lin >> 3;
  const int q = s / nbn;
  const int bm = xcd * 16 + q;
  const int bn = s - q * nbn;
  const int tid = threadIdx.x;
  const int wave = tid >> 6;
  const int lane = tid & 63;
  const int ln = lane & 15;
  const int quad = lane >> 4;
  const int wm = (wave >> 1) * 64;
  const int wn = (wave & 1) * 64;
  const int srow = tid >> 2;
  const int scol = (tid & 3) * 8;

  const size_t koff = (size_t)split * K;
  const u16* Ab = A + koff + (size_t)(bm * 128) * lda + scol;
  const u16* Bb = Bt + koff + (size_t)(bn * 128) * ldb + scol;
  char* ldsA = (char*)As + wave * 1024;
  char* ldsB = (char*)Bs + wave * 1024;

  f32x4 acc[4][4];
#pragma unroll
  for (int i = 0; i < 4; ++i)
#pragma unroll
    for (int j = 0; j < 4; ++j) acc[i][j] = (f32x4){0.f, 0.f, 0.f, 0.f};

  for (int k0 = 0; k0 < K; k0 += 32) {
    gl2lds16(Ab + (size_t)srow * lda + k0, ldsA);
    gl2lds16(Ab + (size_t)(srow + 64) * lda + k0, ldsA + 4096);
    gl2lds16(Bb + (size_t)srow * ldb + k0, ldsB);
    gl2lds16(Bb + (size_t)(srow + 64) * ldb + k0, ldsB + 4096);
    __syncthreads();
    bf16x8 af[4], bfr[4];
#pragma unroll
    for (int i = 0; i < 4; ++i)
      af[i] = *(const bf16x8*)(As + (wm + i * 16 + ln) * 32 + quad * 8);
#pragma unroll
    for (int j = 0; j < 4; ++j)
      bfr[j] = *(const bf16x8*)(Bs + (wn + j * 16 + ln) * 32 + quad * 8);
#pragma unroll
    for (int i = 0; i < 4; ++i)
#pragma unroll
      for (int j = 0; j < 4; ++j)
        acc[i][j] = __builtin_amdgcn_mfma_f32_16x16x32_bf16(af[i], bfr[j], acc[i][j], 0, 0, 0);
    __syncthreads();
  }

  const size_t cbase = (size_t)split * ((size_t)16384 * N);
  const bool res2 = (RES == 2) && (!SPLIT || split == 0);
#pragma unroll
  for (int i = 0; i < 4; ++i) {
#pragma unroll
    for (int r = 0; r < 4; ++r) {
      const int row = bm * 128 + wm + i * 16 + quad * 4 + r;
#pragma unroll
      for (int j = 0; j < 4; ++j) {
        const int col = bn * 128 + wn + j * 16 + ln;
        float v = acc[i][j][r];
        if (bias) v += bias[col];
        if (RES == 1) v += ResF[(size_t)row * N + col];
        if (RES == 2) { if (res2) v += b2f(ResB[(size_t)row * N + col]); }
        if (RELU) v = fmaxf(v, 0.f);
        if (OUTF) outF[cbase + (size_t)row * N + col] = v;
        if (OUTB) outB[cbase + (size_t)row * N + col] = f2b(v);
      }
    }
  }
}

// ---------------------------------------------------------------------------
// Per-batch Gram q@k^T with fused diag/anti-diag reduction. Epilogue v2:
// all 4 waves write transposed bf16 quadrant tiles in parallel (ds_write_b64),
// then each thread OWNS one output offset o and sums the valid quadrants.
// Grid (8 batches -> XCD, 16 bn, 16 bm).
// ---------------------------------------------------------------------------
__global__ __launch_bounds__(256)
void gram_diag(const u16* __restrict__ qkv, float* __restrict__ csig,
               float* __restrict__ wsig) {
  __shared__ u16 As[128 * 32];
  __shared__ u16 Bs[128 * 32];
  __shared__ u16 qt[4][64 * 68];  // transposed quadrants: qt[w][col*68+row]
  const int bt = blockIdx.x;
  const int bn = blockIdx.y;
  const int bm = blockIdx.z;
  const int tid = threadIdx.x;
  const int wave = tid >> 6;
  const int lane = tid & 63;
  const int ln = lane & 15;
  const int quad = lane >> 4;
  const int wm = (wave >> 1) * 64;
  const int wn = (wave & 1) * 64;
  const int srow = tid >> 2;
  const int scol = (tid & 3) * 8;

  const u16* Qb = qkv + (size_t)bt * kL * 1536 + (size_t)(bm * 128) * 1536 + scol;
  const u16* Kb = qkv + (size_t)bt * kL * 1536 + 512 + (size_t)(bn * 128) * 1536 + scol;
  char* ldsA = (char*)As + wave * 1024;
  char* ldsB = (char*)Bs + wave * 1024;

  f32x4 acc[4][4];
#pragma unroll
  for (int i = 0; i < 4; ++i)
#pragma unroll
    for (int j = 0; j < 4; ++j) acc[i][j] = (f32x4){0.f, 0.f, 0.f, 0.f};

  for (int k0 = 0; k0 < 512; k0 += 32) {
    gl2lds16(Qb + (size_t)srow * 1536 + k0, ldsA);
    gl2lds16(Qb + (size_t)(srow + 64) * 1536 + k0, ldsA + 4096);
    gl2lds16(Kb + (size_t)srow * 1536 + k0, ldsB);
    gl2lds16(Kb + (size_t)(srow + 64) * 1536 + k0, ldsB + 4096);
    __syncthreads();
    bf16x8 af[4], bfr[4];
#pragma unroll
    for (int i = 0; i < 4; ++i)
      af[i] = *(const bf16x8*)(As + (wm + i * 16 + ln) * 32 + quad * 8);
#pragma unroll
    for (int j = 0; j < 4; ++j)
      bfr[j] = *(const bf16x8*)(Bs + (wn + j * 16 + ln) * 32 + quad * 8);
#pragma unroll
    for (int i = 0; i < 4; ++i)
#pragma unroll
      for (int j = 0; j < 4; ++j)
        acc[i][j] = __builtin_amdgcn_mfma_f32_16x16x32_bf16(af[i], bfr[j], acc[i][j], 0, 0, 0);
    __syncthreads();
  }

  // all waves write their transposed quadrant concurrently: row index packs 4
  u16* T = &qt[wave][0];
#pragma unroll
  for (int i = 0; i < 4; ++i) {
#pragma unroll
    for (int j = 0; j < 4; ++j) {
      u16 p[4];
#pragma unroll
      for (int r = 0; r < 4; ++r) p[r] = f2b(acc[i][j][r]);
      *(ushort4*)&T[(j * 16 + ln) * 68 + i * 16 + quad * 4] = *(const ushort4*)p;
    }
  }
  __syncthreads();

  // thread o owns output offset o: c index o -> row-col = o-127, w index o -> row+col = o
  const int o = tid;
  // quadrant (wm-wn): {0,-64,64,0} ; (wm+wn): {0,64,64,128}
  const int offc[4] = {0, -64, 64, 0};
  const int offw[4] = {0, 64, 64, 128};
  float csum = 0.f, wsum = 0.f;
#pragma unroll
  for (int w4 = 0; w4 < 4; ++w4) {
    const u16* Tq = &qt[w4][0];
    const int d = (o - 127) - offc[w4];
    if (d >= -63 && d <= 63) {
      const int clo = d < 0 ? -d : 0;
      const int chi = d < 0 ? 63 : 63 - d;
      float s = 0.f;
      for (int cc = clo; cc <= chi; ++cc) s += b2f(Tq[cc * 68 + cc + d]);
      csum += s;
    }
    const int ss = o - offw[w4];
    if (ss >= 0 && ss <= 126) {
      const int clo = ss < 64 ? 0 : ss - 63;
      const int chi = ss < 64 ? ss : 63;
      float s = 0.f;
      for (int cc = clo; cc <= chi; ++cc) s += b2f(Tq[cc * 68 + ss - cc]);
      wsum += s;
    }
  }
  if (o < 255) {
    const int i0 = bm * 128, j0 = bn * 128;
    atomicAdd(&csig[bt * kL + ((i0 - j0 + o - 127) & kLMask)], csum);
    atomicAdd(&wsig[bt * kL + ((i0 + j0 + o) & kLMask)], wsum);
  }
}

__global__ __launch_bounds__(256)
void cast_f2b_kernel(const float* __restrict__ X, u16* __restrict__ Y) {
  const int i = (blockIdx.x * 256 + threadIdx.x) * 4;
  float4 v = *(const float4*)(X + i);
  ushort4 o;
  o.x = f2b(v.x); o.y = f2b(v.y); o.z = f2b(v.z); o.w = f2b(v.w);
  *(ushort4*)(Y + i) = o;
}

// 4x 512x512 W[K][N] fp32 -> Wt[N][K] bf16, z-batched
__global__ __launch_bounds__(256)
void transpose4_kernel(const float* __restrict__ W0, const float* __restrict__ W1,
                       const float* __restrict__ W2, const float* __restrict__ W3,
                       u16* __restrict__ dst) {
  __shared__ float t[32][33];
  const int z = blockIdx.z;
  const float* W = z == 0 ? W0 : z == 1 ? W1 : z == 2 ? W2 : W3;
  u16* Wt = dst + (size_t)z * 512 * 512;
  const int k0 = blockIdx.y * 32, n0 = blockIdx.x * 32;
  const int tx = threadIdx.x & 31, ty = threadIdx.x >> 5;
  for (int r = ty; r < 32; r += 8)
    t[r][tx] = W[(size_t)(k0 + r) * 512 + n0 + tx];
  __syncthreads();
  for (int r = ty; r < 32; r += 8)
    Wt[(size_t)(n0 + r) * 512 + k0 + tx] = f2b(t[tx][r]);
}

// generic W[K][N] fp32 -> Wt[N][K] bf16
__global__ __launch_bounds__(256)
void transpose_cast_kernel(const float* __restrict__ W, u16* __restrict__ Wt,
                           int K, int N) {
  __shared__ float t[32][33];
  const int k0 = blockIdx.y * 32, n0 = blockIdx.x * 32;
  const int tx = threadIdx.x & 31, ty = threadIdx.x >> 5;
  for (int r = ty; r < 32; r += 8)
    t[r][tx] = W[(size_t)(k0 + r) * N + n0 + tx];
  __syncthreads();
  for (int r = ty; r < 32; r += 8)
    Wt[(size_t)(n0 + r) * K + k0 + tx] = f2b(t[tx][r]);
}

__global__ void concat_bias_kernel(const float* __restrict__ bq,
                                   const float* __restrict__ bk,
                                   const float* __restrict__ bv,
                                   float* __restrict__ o) {
  const int i = blockIdx.x * 256 + threadIdx.x;
  const float* s = i < 512 ? bq : (i < 1024 ? bk : bv);
  o[i] = s[i & 511];
}

// meanv(tau) += [cp-term (z==0) + (1/L) sum_{t in chunk} cm(t)*(G(tau+t)+G(tau-t))]/512
__global__ __launch_bounds__(256)
void meanv_kernel(const float* __restrict__ csig, const float* __restrict__ wsig,
                  float* __restrict__ meanv) {
  __shared__ float cm[512];
  __shared__ float G[kL];
  const int b = blockIdx.y;
  const int z = blockIdx.z;
  const int tau = blockIdx.x * 256 + threadIdx.x;
  for (int e = threadIdx.x; e < kL; e += 256) {
    if (e & 1) {
      float sv, cv;
      __sincosf((float)e * (3.14159265358979323846f / 2048.0f), &sv, &cv);
      G[e] = cv / sv;
    } else {
      G[e] = 0.f;
    }
  }
  for (int e = threadIdx.x; e < 512; e += 256) {
    const int t = z * 512 + e;
    cm[e] = 0.5f * (csig[b * kL + t] - wsig[b * kL + t]);
  }
  __syncthreads();
  float S = 0.f;
  for (int tt = 0; tt < 512; ++tt) {
    const int t = z * 512 + tt;
    S += cm[tt] * (G[(tau + t) & kLMask] + G[(tau - t) & kLMask]);
  }
  float res = S * (1.0f / 2048.0f);
  if (z == 0) {
    const float cpt = 0.5f * (csig[b * kL + tau] + wsig[b * kL + tau]);
    const int mt = (kL - tau) & kLMask;
    const float cpm = 0.5f * (csig[b * kL + mt] + wsig[b * kL + mt]);
    res += 0.5f * (cpt + cpm);
  }
  atomicAdd(&meanv[b * kL + tau], res * (1.0f / 512.0f));
}

// stage 1: per-256-chunk local top-15. Grid (8 chunks, 8 batches).
__global__ __launch_bounds__(256)
void topk1_kernel(const float* __restrict__ meanv, float* __restrict__ candv,
                  int* __restrict__ candi) {
  __shared__ float f[256];
  __shared__ float rv[256];
  __shared__ int ri[256];
  const int chunk = blockIdx.x;
  const int b = blockIdx.y;
  const int t = threadIdx.x;
  const int gi = chunk * 256 + t;
  f[t] = meanv[b * kL + gi];
  __syncthreads();
  const int obase = (b * 8 + chunk) * kTopk;
  for (int round = 0; round < kTopk; ++round) {
    rv[t] = f[t];
    ri[t] = gi;
    __syncthreads();
    for (int s = 128; s > 0; s >>= 1) {
      if (t < s) {
        const float v2 = rv[t + s];
        const int i2 = ri[t + s];
        if (v2 > rv[t] || (v2 == rv[t] && i2 < ri[t])) { rv[t] = v2; ri[t] = i2; }
      }
      __syncthreads();
    }
    if (t == 0) {
      candv[obase + round] = rv[0];
      candi[obase + round] = ri[0];
      f[ri[0] & 255] = -INFINITY;
    }
    __syncthreads();
  }
}

// stage 2: merge 8x15=120 candidates -> global top-15 + softmax. Grid (8).
__global__ __launch_bounds__(128)
void topk2_kernel(const float* __restrict__ candv, const int* __restrict__ candi,
                  float* __restrict__ wts, int* __restrict__ dly) {
  __shared__ float f[128];
  __shared__ int fi[128];
  __shared__ float rv[128];
  __shared__ int ri[128];
  __shared__ float topv[kTopk];
  __shared__ int topi[kTopk];
  const int b = blockIdx.x;
  const int t = threadIdx.x;
  if (t < 120) {
    f[t] = candv[b * 120 + t];
    fi[t] = candi[b * 120 + t];
  } else {
    f[t] = -INFINITY;
    fi[t] = 1 << 30;
  }
  __syncthreads();
  for (int round = 0; round < kTopk; ++round) {
    rv[t] = f[t];
    ri[t] = t;
    __syncthreads();
    for (int s = 64; s > 0; s >>= 1) {
      if (t < s) {
        const float v2 = rv[t + s];
        const int i2 = ri[t + s];
        if (v2 > rv[t] || (v2 == rv[t] && fi[i2] < fi[ri[t]])) { rv[t] = v2; ri[t] = i2; }
      }
      __syncthreads();
    }
    if (t == 0) {
      topv[round] = rv[0];
      topi[round] = fi[ri[0]];
      f[ri[0]] = -INFINITY;
    }
    __syncthreads();
  }
  if (t == 0) {
    const float m = topv[0];
    float sum = 0.f;
    float e[kTopk];
    for (int i = 0; i < kTopk; ++i) { e[i] = expf(topv[i] - m); sum += e[i]; }
    for (int i = 0; i < kTopk; ++i) {
      wts[b * 16 + i] = e[i] / sum;
      dly[b * 16 + i] = topi[i];
    }
  }
}

// attn_in[b,l,c] = sum_t w_t * v[b,(l+delay_t)%L,c]; 1-D grid, batch = lin%8
__global__ __launch_bounds__(256)
void agg_kernel(const u16* __restrict__ qkv, const float* __restrict__ wts,
                const int* __restrict__ dly, u16* __restrict__ out) {
  __shared__ float w[16];
  __shared__ int dl[16];
  const int lin = blockIdx.x;
  const int b = lin & 7;
  if (threadIdx.x < kTopk) {
    w[threadIdx.x] = wts[b * 16 + threadIdx.x];
    dl[threadIdx.x] = dly[b * 16 + threadIdx.x];
  }
  __syncthreads();
  const int l = (lin >> 3) * 4 + (threadIdx.x >> 6);
  const int co = (threadIdx.x & 63) * 8;
  const u16* vb = qkv + (size_t)b * kL * 1536 + 1024 + co;
  float a[8] = {0.f, 0.f, 0.f, 0.f, 0.f, 0.f, 0.f, 0.f};
  for (int t = 0; t < kTopk; ++t) {
    const int row = (l + dl[t]) & kLMask;
    float4 rv = *(const float4*)(vb + (size_t)row * 1536);
    const u16* p = (const u16*)&rv;
    const float wt = w[t];
#pragma unroll
    for (int e = 0; e < 8; ++e) a[e] += wt * b2f(p[e]);
  }
  u16 ob[8];
#pragma unroll
  for (int e = 0; e < 8; ++e) ob[e] = f2b(a[e]);
  *(float4*)(out + ((size_t)b * kL + l) * kD + co) = *(const float4*)ob;
}

// decomp, bf16 in -> bf16 out (streaming 25-tap clamped MA)
__global__ __launch_bounds__(256)
void decomp_b2b(const u16* __restrict__ X, u16* __restrict__ OB) {
  const int c = blockIdx.x * 256 + threadIdx.x;
  const int b = blockIdx.y;
  const int l0 = blockIdx.z * 64;
  const u16* base = X + (size_t)b * kL * kD + c;
  float sum = 0.f;
#pragma unroll
  for (int m = -12; m <= 12; ++m) {
    int lm = l0 + m;
    lm = lm < 0 ? 0 : (lm > kL - 1 ? kL - 1 : lm);
    sum += b2f(base[(size_t)lm * kD]);
  }
#pragma unroll 4
  for (int l = l0; l < l0 + 64; ++l) {
    const float val = b2f(base[(size_t)l * kD]);
    OB[((size_t)b * kL + l) * kD + c] = f2b(val - sum * (1.0f / 25.0f));
    const int la = l + 13 > kL - 1 ? kL - 1 : l + 13;
    const int lr = l - 12 < 0 ? 0 : l - 12;
    sum += b2f(base[(size_t)la * kD]) - b2f(base[(size_t)lr * kD]);
  }
}

// decomp of (X1+X2), fp32 -> fp32 out
__global__ __launch_bounds__(256)
void decomp_ff2(const float* __restrict__ X1, const float* __restrict__ X2,
                float* __restrict__ OF) {
  const int c = blockIdx.x * 256 + threadIdx.x;
  const int b = blockIdx.y;
  const int l0 = blockIdx.z * 64;
  const size_t off = (size_t)b * kL * kD + c;
  const float* b1 = X1 + off;
  const float* b2 = X2 + off;
  float sum = 0.f;
#pragma unroll
  for (int m = -12; m <= 12; ++m) {
    int lm = l0 + m;
    lm = lm < 0 ? 0 : (lm > kL - 1 ? kL - 1 : lm);
    sum += b1[(size_t)lm * kD] + b2[(size_t)lm * kD];
  }
#pragma unroll 4
  for (int l = l0; l < l0 + 64; ++l) {
    const float val = b1[(size_t)l * kD] + b2[(size_t)l * kD];
    OF[((size_t)b * kL + l) * kD + c] = val - sum * (1.0f / 25.0f);
    const int la = l + 13 > kL - 1 ? kL - 1 : l + 13;
    const int lr = l - 12 < 0 ? 0 : l - 12;
    sum += b1[(size_t)la * kD] + b2[(size_t)la * kD]
         - b1[(size_t)lr * kD] - b2[(size_t)lr * kD];
  }
}

extern "C" void kernel_launch(void* const* d_in, const int* in_sizes, int n_in,
                              void* d_out, int out_size, void* d_ws, size_t ws_size,
                              hipStream_t stream) {
  const float* x  = (const float*)d_in[0];
  const float* Wq = (const float*)d_in[1];
  const float* bq = (const float*)d_in[2];
  const float* Wk = (const float*)d_in[3];
  const float* bk = (const float*)d_in[4];
  const float* Wv = (const float*)d_in[5];
  const float* bv = (const float*)d_in[6];
  const float* Wo = (const float*)d_in[7];
  const float* bo = (const float*)d_in[8];
  const float* W1 = (const float*)d_in[9];
  const float* W2 = (const float*)d_in[10];
  float* out = (float*)d_out;

  const size_t MiB = 1u << 20;
  const size_t NBLD = (size_t)kB * kL * kD;  // 8,388,608
  char* base = (char*)d_ws;
  u16*   qkvb  = (u16*)(base);               // [0,48)
  u16*   xb    = (u16*)(base + 48 * MiB);    // [48,64) ; aggb aliases
  u16*   aggb  = xb;
  u16*   xrb   = (u16*)(base + 64 * MiB);    // [64,80)
  u16*   s1b   = (u16*)(base + 80 * MiB);    // [80,96)
  u16*   midb  = (u16*)(base + 96 * MiB);    // [96,160)
  float* s2p   = (float*)(base);             // [0,64) after qkvb/aggb dead
  u16*   Wqkvt = (u16*)(base + 160 * MiB);   // 2 MiB (incl Wot as slot 3)
  u16*   Wot   = Wqkvt + 3 * 512 * 512;
  u16*   W1t   = (u16*)(base + 162 * MiB);   // 2 MiB
  u16*   W2t   = (u16*)(base + 164 * MiB);   // 2 MiB
  float* bqkv  = (float*)(base + 166 * MiB);
  float* csig  = bqkv + 2048;
  float* wsig  = csig + kB * kL;
  float* meanv = wsig + kB * kL;
  float* wtsf  = meanv + kB * kL;
  int*   dlyi  = (int*)(wtsf + kB * 16);
  float* candv = (float*)(dlyi + kB * 16);   // 8*8*15
  int*   candi = (int*)(candv + kB * 8 * kTopk);

  const dim3 blk(256);

  // input cast + weight prep
  cast_f2b_kernel<<<(int)(NBLD / 1024), blk, 0, stream>>>(x, xb);
  transpose4_kernel<<<dim3(16, 16, 4), blk, 0, stream>>>(Wq, Wk, Wv, Wo, Wqkvt);
  transpose_cast_kernel<<<dim3(64, 16), blk, 0, stream>>>(W1, W1t, 512, 2048);
  transpose_cast_kernel<<<dim3(16, 64), blk, 0, stream>>>(W2, W2t, 2048, 512);
  concat_bias_kernel<<<dim3(6), blk, 0, stream>>>(bq, bk, bv, bqkv);
  hipMemsetAsync(csig, 0, 3 * kB * kL * sizeof(float), stream);  // csig,wsig,meanv

  // fused QKV projection -> qkvb bf16
  mfma_gemm<0, 0, 0, 1, 0><<<dim3(1536), blk, 0, stream>>>(
      xb, Wqkvt, bqkv, nullptr, nullptr, nullptr, qkvb, 1536, 512, 512, 512, 12);

  // Gram + fused diag reduction (no Gram materialization)
  gram_diag<<<dim3(8, 16, 16), blk, 0, stream>>>(qkvb, csig, wsig);

  meanv_kernel<<<dim3(8, 8, 4), blk, 0, stream>>>(csig, wsig, meanv);
  topk1_kernel<<<dim3(8, 8), blk, 0, stream>>>(meanv, candv, candi);
  topk2_kernel<<<dim3(8), dim3(128), 0, stream>>>(candv, candi, wtsf, dlyi);

  // delay aggregation -> aggb bf16 ; Wo + bias + residual(x) -> xrb bf16
  agg_kernel<<<dim3(4096), blk, 0, stream>>>(qkvb, wtsf, dlyi, aggb);
  mfma_gemm<0, 0, 0, 1, 1><<<dim3(512), blk, 0, stream>>>(
      aggb, Wot, bo, x, nullptr, nullptr, xrb, 512, 512, 512, 512, 4);

  // decomp 1 -> s1b bf16
  decomp_b2b<<<dim3(2, 8, 32), blk, 0, stream>>>(xrb, s1b);

  // FFN1: relu(s1b @ W1) -> midb bf16
  mfma_gemm<0, 1, 0, 1, 0><<<dim3(2048), blk, 0, stream>>>(
      s1b, W1t, nullptr, nullptr, nullptr, nullptr, midb, 2048, 512, 512, 512, 16);
  // FFN2 split-K=2 (one dispatch, 1024 blocks)
  mfma_gemm<1, 0, 1, 0, 2><<<dim3(1024), blk, 0, stream>>>(
      midb, W2t, nullptr, nullptr, s1b, s2p, nullptr, 512, 1024, 2048, 2048, 4);

  // decomp 2 over (partial0 + partial1) -> out fp32
  decomp_ff2<<<dim3(2, 8, 32), blk, 0, stream>>>(s2p, s2p + NBLD, out);
}

// Round 6
// 519.727 us; speedup vs baseline: 6.3911x; 1.0253x over previous
//
#include <hip/hip_runtime.h>
#include <math.h>

namespace {
constexpr int kB = 8;
constexpr int kL = 2048;
constexpr int kD = 512;
constexpr int kTopk = 15;
constexpr int kLMask = 2047;
}

typedef unsigned short u16;
using f32x4 = __attribute__((ext_vector_type(4))) float;
using bf16x8 = __attribute__((ext_vector_type(8))) __bf16;

__device__ __forceinline__ u16 f2b(float f) {
  unsigned u = __float_as_uint(f);
  unsigned r = (u + 0x7fffu + ((u >> 16) & 1u)) >> 16;  // RNE
  return (u16)r;
}
__device__ __forceinline__ float b2f(u16 u) {
  return __uint_as_float(((unsigned)u) << 16);
}

typedef __attribute__((address_space(3))) unsigned int lds_u32;
typedef __attribute__((address_space(1))) const unsigned int glb_u32;
__device__ __forceinline__ void gl2lds16(const void* g, void* l) {
  __builtin_amdgcn_global_load_lds((glb_u32*)g, (lds_u32*)l, 16, 0, 0);
}

// ---------------------------------------------------------------------------
// bf16 MFMA GEMM, m97-style: 128x128 tile, BK=32, global_load_lds staging.
// 1-D swizzled grid: XCD = lin%8 owns complete A row-strips (M=16384 fixed).
// SPLIT: grid doubled; split = lin>>9 takes K-half, writes to out + split*M*N.
// RES: 0 none, 1 fp32 (always), 2 bf16 (split 0 only).
// ---------------------------------------------------------------------------
template <int SPLIT, int RELU, int OUTF, int OUTB, int RES>
__global__ __launch_bounds__(256)
void mfma_gemm(const u16* __restrict__ A, const u16* __restrict__ Bt,
               const float* __restrict__ bias, const float* __restrict__ ResF,
               const u16* __restrict__ ResB, float* __restrict__ outF,
               u16* __restrict__ outB, int N, int K, int lda, int ldb, int nbn) {
  __shared__ u16 As[128 * 32];
  __shared__ u16 Bs[128 * 32];
  int lin = blockIdx.x;
  int split = 0;
  if (SPLIT) { split = lin >> 9; lin &= 511; }
  const int xcd = lin & 7;
  const int s = lin >> 3;
  const int q = s / nbn;
  const int bm = xcd * 16 + q;
  const int bn = s - q * nbn;
  const int tid = threadIdx.x;
  const int wave = tid >> 6;
  const int lane = tid & 63;
  const int ln = lane & 15;
  const int quad = lane >> 4;
  const int wm = (wave >> 1) * 64;
  const int wn = (wave & 1) * 64;
  const int srow = tid >> 2;
  const int scol = (tid & 3) * 8;

  const size_t koff = (size_t)split * K;
  const u16* Ab = A + koff + (size_t)(bm * 128) * lda + scol;
  const u16* Bb = Bt + koff + (size_t)(bn * 128) * ldb + scol;
  char* ldsA = (char*)As + wave * 1024;
  char* ldsB = (char*)Bs + wave * 1024;

  f32x4 acc[4][4];
#pragma unroll
  for (int i = 0; i < 4; ++i)
#pragma unroll
    for (int j = 0; j < 4; ++j) acc[i][j] = (f32x4){0.f, 0.f, 0.f, 0.f};

  for (int k0 = 0; k0 < K; k0 += 32) {
    gl2lds16(Ab + (size_t)srow * lda + k0, ldsA);
    gl2lds16(Ab + (size_t)(srow + 64) * lda + k0, ldsA + 4096);
    gl2lds16(Bb + (size_t)srow * ldb + k0, ldsB);
    gl2lds16(Bb + (size_t)(srow + 64) * ldb + k0, ldsB + 4096);
    __syncthreads();
    bf16x8 af[4], bfr[4];
#pragma unroll
    for (int i = 0; i < 4; ++i)
      af[i] = *(const bf16x8*)(As + (wm + i * 16 + ln) * 32 + quad * 8);
#pragma unroll
    for (int j = 0; j < 4; ++j)
      bfr[j] = *(const bf16x8*)(Bs + (wn + j * 16 + ln) * 32 + quad * 8);
#pragma unroll
    for (int i = 0; i < 4; ++i)
#pragma unroll
      for (int j = 0; j < 4; ++j)
        acc[i][j] = __builtin_amdgcn_mfma_f32_16x16x32_bf16(af[i], bfr[j], acc[i][j], 0, 0, 0);
    __syncthreads();
  }

  const size_t cbase = (size_t)split * ((size_t)16384 * N);
  const bool res2 = (RES == 2) && (!SPLIT || split == 0);
#pragma unroll
  for (int i = 0; i < 4; ++i) {
#pragma unroll
    for (int r = 0; r < 4; ++r) {
      const int row = bm * 128 + wm + i * 16 + quad * 4 + r;
#pragma unroll
      for (int j = 0; j < 4; ++j) {
        const int col = bn * 128 + wn + j * 16 + ln;
        float v = acc[i][j][r];
        if (bias) v += bias[col];
        if (RES == 1) v += ResF[(size_t)row * N + col];
        if (RES == 2) { if (res2) v += b2f(ResB[(size_t)row * N + col]); }
        if (RELU) v = fmaxf(v, 0.f);
        if (OUTF) outF[cbase + (size_t)row * N + col] = v;
        if (OUTB) outB[cbase + (size_t)row * N + col] = f2b(v);
      }
    }
  }
}

// ---------------------------------------------------------------------------
// Correlation spectra via packed complex FFT. One block = one batch (XCD) x
// 4 channels. Z = FFT(q + i*k) (2048-pt radix-2 DIF, natural input, bit-rev
// output). Per frequency f: Q=(Z_f+conj(Z_{N-f}))/2, K=(Z_f-conj(Z_{N-f}))/2i;
// accumulate A_f = sum ReQ*ReK, B_f = sum ImQ*ImK into per-block partials.
// Twiddles in stage-padded table tw[(m-1)+j] = e^{-i*pi*j/m} (conflict-free).
// ---------------------------------------------------------------------------
__global__ __launch_bounds__(256)
void fft_corr(const u16* __restrict__ qkv, float* __restrict__ pA,
              float* __restrict__ pB) {
  __shared__ u16 stq[4 * 2048];
  __shared__ u16 stk[4 * 2048];
  __shared__ float re[2048];
  __shared__ float im[2048];
  __shared__ float twc[2047];
  __shared__ float tws[2047];
  const int blk = blockIdx.x;
  const int b = blk & 7;          // batch -> XCD
  const int g = blk >> 3;         // channel group 0..127
  const int t = threadIdx.x;

  for (int e = t; e < 2047; e += 256) {
    const int s = 31 - __clz(e + 1);
    const int m = 1 << s;
    const int j = e + 1 - m;
    float sv, cv;
    __sincosf((float)j * 3.14159265358979323846f / (float)m, &sv, &cv);
    twc[e] = cv;
    tws[e] = sv;
  }
  const u16* qb = qkv + (size_t)b * kL * 1536 + g * 4;
#pragma unroll
  for (int p = 0; p < 8; ++p) {
    const int row = p * 256 + t;
    *(ushort4*)&stq[row * 4] = *(const ushort4*)(qb + (size_t)row * 1536);
    *(ushort4*)&stk[row * 4] = *(const ushort4*)(qb + (size_t)row * 1536 + 512);
  }

  float accA[8], accB[8];
#pragma unroll
  for (int i = 0; i < 8; ++i) { accA[i] = 0.f; accB[i] = 0.f; }

  for (int c = 0; c < 4; ++c) {
    __syncthreads();
#pragma unroll
    for (int p = 0; p < 8; ++p) {
      const int n = p * 256 + t;
      re[n] = b2f(stq[n * 4 + c]);
      im[n] = b2f(stk[n * 4 + c]);
    }
    for (int s = 10; s >= 0; --s) {
      __syncthreads();
      const int m = 1 << s;
      for (int p = 0; p < 4; ++p) {
        const int id = p * 256 + t;
        const int j = id & (m - 1);
        const int i0 = ((id >> s) << (s + 1)) + j;
        const int i1 = i0 + m;
        const int kk = (m - 1) + j;
        const float ar = re[i0], ai = im[i0];
        const float br = re[i1], bi = im[i1];
        re[i0] = ar + br;
        im[i0] = ai + bi;
        const float dr = ar - br, di = ai - bi;
        const float cv = twc[kk], sv = tws[kk];
        re[i1] = dr * cv + di * sv;   // (dr + i di) * (cv - i sv)
        im[i1] = di * cv - dr * sv;
      }
    }
    __syncthreads();
#pragma unroll
    for (int i = 0; i < 8; ++i) {
      const int pos = (i < 4) ? (i * 256 + t) : (1024 + (i - 4) * 256 + t);
      const int f = __brev((unsigned)pos) >> 21;       // freq at this position
      if (f <= 1024) {
        const int fm = (2048 - f) & 2047;
        const int pm = __brev((unsigned)fm) >> 21;
        const float zr = re[pos], zi = im[pos];
        const float mr = re[pm], mi = im[pm];
        const float ReQ = 0.5f * (zr + mr);
        const float ImQ = 0.5f * (zi - mi);
        const float ReK = 0.5f * (zi + mi);
        const float ImK = 0.5f * (mr - zr);
        accA[i] += ReQ * ReK;
        accB[i] += ImQ * ImK;
      }
    }
  }
  float* pAb = pA + (size_t)blk * 1025;
  float* pBb = pB + (size_t)blk * 1025;
#pragma unroll
  for (int i = 0; i < 8; ++i) {
    const int pos = (i < 4) ? (i * 256 + t) : (1024 + (i - 4) * 256 + t);
    const int f = __brev((unsigned)pos) >> 21;
    if (f <= 1024) { pAb[f] = accA[i]; pBb[f] = accB[i]; }
  }
}

// sum 128 group partials -> Asp/Bsp. Grid (8 batches, 5 freq chunks).
__global__ __launch_bounds__(256)
void reduceAB(const float* __restrict__ pA, const float* __restrict__ pB,
              float* __restrict__ Asp, float* __restrict__ Bsp) {
  const int b = blockIdx.x;
  const int f = blockIdx.y * 256 + threadIdx.x;
  if (f > 1024) return;
  float sa = 0.f, sb = 0.f;
  for (int g = 0; g < 128; ++g) {
    const size_t idx = (size_t)((g << 3) | b) * 1025 + f;
    sa += pA[idx];
    sb += pB[idx];
  }
  Asp[b * 1025 + f] = sa;
  Bsp[b * 1025 + f] = sb;
}

// meanv = irfft(A - iB)/512 via inverse complex FFT (DIT, bit-rev input).
__global__ __launch_bounds__(256)
void ifft_meanv(const float* __restrict__ Asp, const float* __restrict__ Bsp,
                float* __restrict__ meanv) {
  __shared__ float re[2048];
  __shared__ float im[2048];
  __shared__ float twc[2047];
  __shared__ float tws[2047];
  const int b = blockIdx.x;
  const int t = threadIdx.x;
  for (int e = t; e < 2047; e += 256) {
    const int s = 31 - __clz(e + 1);
    const int m = 1 << s;
    const int j = e + 1 - m;
    float sv, cv;
    __sincosf((float)j * 3.14159265358979323846f / (float)m, &sv, &cv);
    twc[e] = cv;
    tws[e] = sv;
  }
#pragma unroll
  for (int i = 0; i < 8; ++i) {
    const int f = i * 256 + t;
    float Xr, Xi;
    if (f <= 1024) {
      Xr = Asp[b * 1025 + f];
      Xi = (f == 0 || f == 1024) ? 0.f : -Bsp[b * 1025 + f];
    } else {
      const int gg = 2048 - f;
      Xr = Asp[b * 1025 + gg];
      Xi = Bsp[b * 1025 + gg];
    }
    const int pos = __brev((unsigned)f) >> 21;
    re[pos] = Xr;
    im[pos] = Xi;
  }
  for (int s = 0; s <= 10; ++s) {
    __syncthreads();
    const int m = 1 << s;
    for (int p = 0; p < 4; ++p) {
      const int id = p * 256 + t;
      const int j = id & (m - 1);
      const int i0 = ((id >> s) << (s + 1)) + j;
      const int i1 = i0 + m;
      const int kk = (m - 1) + j;
      const float cv = twc[kk], sv = tws[kk];
      const float br = re[i1], bi = im[i1];
      const float tr = br * cv - bi * sv;   // (br + i bi) * (cv + i sv)
      const float ti = bi * cv + br * sv;
      const float ar = re[i0], ai = im[i0];
      re[i0] = ar + tr;
      im[i0] = ai + ti;
      re[i1] = ar - tr;
      im[i1] = ai - ti;
    }
  }
  __syncthreads();
#pragma unroll
  for (int i = 0; i < 8; ++i) {
    const int n = i * 256 + t;
    meanv[b * kL + n] = re[n] * (1.0f / (2048.0f * 512.0f));
  }
}

__global__ __launch_bounds__(256)
void cast_f2b_kernel(const float* __restrict__ X, u16* __restrict__ Y) {
  const int i = (blockIdx.x * 256 + threadIdx.x) * 4;
  float4 v = *(const float4*)(X + i);
  ushort4 o;
  o.x = f2b(v.x); o.y = f2b(v.y); o.z = f2b(v.z); o.w = f2b(v.w);
  *(ushort4*)(Y + i) = o;
}

// 4x 512x512 W[K][N] fp32 -> Wt[N][K] bf16, z-batched
__global__ __launch_bounds__(256)
void transpose4_kernel(const float* __restrict__ W0, const float* __restrict__ W1,
                       const float* __restrict__ W2, const float* __restrict__ W3,
                       u16* __restrict__ dst) {
  __shared__ float t[32][33];
  const int z = blockIdx.z;
  const float* W = z == 0 ? W0 : z == 1 ? W1 : z == 2 ? W2 : W3;
  u16* Wt = dst + (size_t)z * 512 * 512;
  const int k0 = blockIdx.y * 32, n0 = blockIdx.x * 32;
  const int tx = threadIdx.x & 31, ty = threadIdx.x >> 5;
  for (int r = ty; r < 32; r += 8)
    t[r][tx] = W[(size_t)(k0 + r) * 512 + n0 + tx];
  __syncthreads();
  for (int r = ty; r < 32; r += 8)
    Wt[(size_t)(n0 + r) * 512 + k0 + tx] = f2b(t[tx][r]);
}

// generic W[K][N] fp32 -> Wt[N][K] bf16
__global__ __launch_bounds__(256)
void transpose_cast_kernel(const float* __restrict__ W, u16* __restrict__ Wt,
                           int K, int N) {
  __shared__ float t[32][33];
  const int k0 = blockIdx.y * 32, n0 = blockIdx.x * 32;
  const int tx = threadIdx.x & 31, ty = threadIdx.x >> 5;
  for (int r = ty; r < 32; r += 8)
    t[r][tx] = W[(size_t)(k0 + r) * N + n0 + tx];
  __syncthreads();
  for (int r = ty; r < 32; r += 8)
    Wt[(size_t)(n0 + r) * K + k0 + tx] = f2b(t[tx][r]);
}

__global__ void concat_bias_kernel(const float* __restrict__ bq,
                                   const float* __restrict__ bk,
                                   const float* __restrict__ bv,
                                   float* __restrict__ o) {
  const int i = blockIdx.x * 256 + threadIdx.x;
  const float* s = i < 512 ? bq : (i < 1024 ? bk : bv);
  o[i] = s[i & 511];
}

// stage 1: per-256-chunk local top-15. Grid (8 chunks, 8 batches).
__global__ __launch_bounds__(256)
void topk1_kernel(const float* __restrict__ meanv, float* __restrict__ candv,
                  int* __restrict__ candi) {
  __shared__ float f[256];
  __shared__ float rv[256];
  __shared__ int ri[256];
  const int chunk = blockIdx.x;
  const int b = blockIdx.y;
  const int t = threadIdx.x;
  const int gi = chunk * 256 + t;
  f[t] = meanv[b * kL + gi];
  __syncthreads();
  const int obase = (b * 8 + chunk) * kTopk;
  for (int round = 0; round < kTopk; ++round) {
    rv[t] = f[t];
    ri[t] = gi;
    __syncthreads();
    for (int s = 128; s > 0; s >>= 1) {
      if (t < s) {
        const float v2 = rv[t + s];
        const int i2 = ri[t + s];
        if (v2 > rv[t] || (v2 == rv[t] && i2 < ri[t])) { rv[t] = v2; ri[t] = i2; }
      }
      __syncthreads();
    }
    if (t == 0) {
      candv[obase + round] = rv[0];
      candi[obase + round] = ri[0];
      f[ri[0] & 255] = -INFINITY;
    }
    __syncthreads();
  }
}

// stage 2: merge 8x15=120 candidates -> global top-15 + softmax. Grid (8).
__global__ __launch_bounds__(128)
void topk2_kernel(const float* __restrict__ candv, const int* __restrict__ candi,
                  float* __restrict__ wts, int* __restrict__ dly) {
  __shared__ float f[128];
  __shared__ int fi[128];
  __shared__ float rv[128];
  __shared__ int ri[128];
  __shared__ float topv[kTopk];
  __shared__ int topi[kTopk];
  const int b = blockIdx.x;
  const int t = threadIdx.x;
  if (t < 120) {
    f[t] = candv[b * 120 + t];
    fi[t] = candi[b * 120 + t];
  } else {
    f[t] = -INFINITY;
    fi[t] = 1 << 30;
  }
  __syncthreads();
  for (int round = 0; round < kTopk; ++round) {
    rv[t] = f[t];
    ri[t] = t;
    __syncthreads();
    for (int s = 64; s > 0; s >>= 1) {
      if (t < s) {
        const float v2 = rv[t + s];
        const int i2 = ri[t + s];
        if (v2 > rv[t] || (v2 == rv[t] && fi[i2] < fi[ri[t]])) { rv[t] = v2; ri[t] = i2; }
      }
      __syncthreads();
    }
    if (t == 0) {
      topv[round] = rv[0];
      topi[round] = fi[ri[0]];
      f[ri[0]] = -INFINITY;
    }
    __syncthreads();
  }
  if (t == 0) {
    const float m = topv[0];
    float sum = 0.f;
    float e[kTopk];
    for (int i = 0; i < kTopk; ++i) { e[i] = expf(topv[i] - m); sum += e[i]; }
    for (int i = 0; i < kTopk; ++i) {
      wts[b * 16 + i] = e[i] / sum;
      dly[b * 16 + i] = topi[i];
    }
  }
}

// attn_in[b,l,c] = sum_t w_t * v[b,(l+delay_t)%L,c]; 1-D grid, batch = lin%8
__global__ __launch_bounds__(256)
void agg_kernel(const u16* __restrict__ qkv, const float* __restrict__ wts,
                const int* __restrict__ dly, u16* __restrict__ out) {
  __shared__ float w[16];
  __shared__ int dl[16];
  const int lin = blockIdx.x;
  const int b = lin & 7;
  if (threadIdx.x < kTopk) {
    w[threadIdx.x] = wts[b * 16 + threadIdx.x];
    dl[threadIdx.x] = dly[b * 16 + threadIdx.x];
  }
  __syncthreads();
  const int l = (lin >> 3) * 4 + (threadIdx.x >> 6);
  const int co = (threadIdx.x & 63) * 8;
  const u16* vb = qkv + (size_t)b * kL * 1536 + 1024 + co;
  float a[8] = {0.f, 0.f, 0.f, 0.f, 0.f, 0.f, 0.f, 0.f};
  for (int t = 0; t < kTopk; ++t) {
    const int row = (l + dl[t]) & kLMask;
    float4 rv = *(const float4*)(vb + (size_t)row * 1536);
    const u16* p = (const u16*)&rv;
    const float wt = w[t];
#pragma unroll
    for (int e = 0; e < 8; ++e) a[e] += wt * b2f(p[e]);
  }
  u16 ob[8];
#pragma unroll
  for (int e = 0; e < 8; ++e) ob[e] = f2b(a[e]);
  *(float4*)(out + ((size_t)b * kL + l) * kD + co) = *(const float4*)ob;
}

// decomp, bf16 in -> bf16 out (streaming 25-tap clamped MA)
__global__ __launch_bounds__(256)
void decomp_b2b(const u16* __restrict__ X, u16* __restrict__ OB) {
  const int c = blockIdx.x * 256 + threadIdx.x;
  const int b = blockIdx.y;
  const int l0 = blockIdx.z * 64;
  const u16* base = X + (size_t)b * kL * kD + c;
  float sum = 0.f;
#pragma unroll
  for (int m = -12; m <= 12; ++m) {
    int lm = l0 + m;
    lm = lm < 0 ? 0 : (lm > kL - 1 ? kL - 1 : lm);
    sum += b2f(base[(size_t)lm * kD]);
  }
#pragma unroll 4
  for (int l = l0; l < l0 + 64; ++l) {
    const float val = b2f(base[(size_t)l * kD]);
    OB[((size_t)b * kL + l) * kD + c] = f2b(val - sum * (1.0f / 25.0f));
    const int la = l + 13 > kL - 1 ? kL - 1 : l + 13;
    const int lr = l - 12 < 0 ? 0 : l - 12;
    sum += b2f(base[(size_t)la * kD]) - b2f(base[(size_t)lr * kD]);
  }
}

// decomp of (X1+X2), fp32 -> fp32 out
__global__ __launch_bounds__(256)
void decomp_ff2(const float* __restrict__ X1, const float* __restrict__ X2,
                float* __restrict__ OF) {
  const int c = blockIdx.x * 256 + threadIdx.x;
  const int b = blockIdx.y;
  const int l0 = blockIdx.z * 64;
  const size_t off = (size_t)b * kL * kD + c;
  const float* b1 = X1 + off;
  const float* b2 = X2 + off;
  float sum = 0.f;
#pragma unroll
  for (int m = -12; m <= 12; ++m) {
    int lm = l0 + m;
    lm = lm < 0 ? 0 : (lm > kL - 1 ? kL - 1 : lm);
    sum += b1[(size_t)lm * kD] + b2[(size_t)lm * kD];
  }
#pragma unroll 4
  for (int l = l0; l < l0 + 64; ++l) {
    const float val = b1[(size_t)l * kD] + b2[(size_t)l * kD];
    OF[((size_t)b * kL + l) * kD + c] = val - sum * (1.0f / 25.0f);
    const int la = l + 13 > kL - 1 ? kL - 1 : l + 13;
    const int lr = l - 12 < 0 ? 0 : l - 12;
    sum += b1[(size_t)la * kD] + b2[(size_t)la * kD]
         - b1[(size_t)lr * kD] - b2[(size_t)lr * kD];
  }
}

extern "C" void kernel_launch(void* const* d_in, const int* in_sizes, int n_in,
                              void* d_out, int out_size, void* d_ws, size_t ws_size,
                              hipStream_t stream) {
  const float* x  = (const float*)d_in[0];
  const float* Wq = (const float*)d_in[1];
  const float* bq = (const float*)d_in[2];
  const float* Wk = (const float*)d_in[3];
  const float* bk = (const float*)d_in[4];
  const float* Wv = (const float*)d_in[5];
  const float* bv = (const float*)d_in[6];
  const float* Wo = (const float*)d_in[7];
  const float* bo = (const float*)d_in[8];
  const float* W1 = (const float*)d_in[9];
  const float* W2 = (const float*)d_in[10];
  float* out = (float*)d_out;

  const size_t MiB = 1u << 20;
  const size_t NBLD = (size_t)kB * kL * kD;  // 8,388,608
  char* base = (char*)d_ws;
  u16*   qkvb  = (u16*)(base);               // [0,48)
  u16*   xb    = (u16*)(base + 48 * MiB);    // [48,64) ; aggb aliases
  u16*   aggb  = xb;
  u16*   xrb   = (u16*)(base + 64 * MiB);    // [64,80)
  u16*   s1b   = (u16*)(base + 80 * MiB);    // [80,96)
  u16*   midb  = (u16*)(base + 96 * MiB);    // [96,160)
  float* s2p   = (float*)(base);             // [0,64) after qkvb/aggb dead
  u16*   Wqkvt = (u16*)(base + 160 * MiB);   // 2 MiB (incl Wot as slot 3)
  u16*   Wot   = Wqkvt + 3 * 512 * 512;
  u16*   W1t   = (u16*)(base + 162 * MiB);   // 2 MiB
  u16*   W2t   = (u16*)(base + 164 * MiB);   // 2 MiB
  float* bqkv  = (float*)(base + 166 * MiB);
  float* Asp   = bqkv + 2048;                // 8 x 1025
  float* Bsp   = Asp + kB * 1025;
  float* meanv = Bsp + kB * 1025;            // 8 x 2048
  float* wtsf  = meanv + kB * kL;
  int*   dlyi  = (int*)(wtsf + kB * 16);
  float* candv = (float*)(dlyi + kB * 16);   // 8*8*15
  int*   candi = (int*)(candv + kB * 8 * kTopk);
  float* pA    = (float*)(base + 167 * MiB); // 1024 x 1025 (~4 MiB)
  float* pB    = (float*)(base + 172 * MiB); // 1024 x 1025

  const dim3 blk(256);

  // input cast + weight prep
  cast_f2b_kernel<<<(int)(NBLD / 1024), blk, 0, stream>>>(x, xb);
  transpose4_kernel<<<dim3(16, 16, 4), blk, 0, stream>>>(Wq, Wk, Wv, Wo, Wqkvt);
  transpose_cast_kernel<<<dim3(64, 16), blk, 0, stream>>>(W1, W1t, 512, 2048);
  transpose_cast_kernel<<<dim3(16, 64), blk, 0, stream>>>(W2, W2t, 2048, 512);
  concat_bias_kernel<<<dim3(6), blk, 0, stream>>>(bq, bk, bv, bqkv);

  // fused QKV projection -> qkvb bf16
  mfma_gemm<0, 0, 0, 1, 0><<<dim3(1536), blk, 0, stream>>>(
      xb, Wqkvt, bqkv, nullptr, nullptr, nullptr, qkvb, 1536, 512, 512, 512, 12);

  // correlation spectra via packed FFTs (replaces Gram + diag + cot-kernel)
  fft_corr<<<dim3(1024), blk, 0, stream>>>(qkvb, pA, pB);
  reduceAB<<<dim3(8, 5), blk, 0, stream>>>(pA, pB, Asp, Bsp);
  ifft_meanv<<<dim3(8), blk, 0, stream>>>(Asp, Bsp, meanv);

  topk1_kernel<<<dim3(8, 8), blk, 0, stream>>>(meanv, candv, candi);
  topk2_kernel<<<dim3(8), dim3(128), 0, stream>>>(candv, candi, wtsf, dlyi);

  // delay aggregation -> aggb bf16 ; Wo + bias + residual(x) -> xrb bf16
  agg_kernel<<<dim3(4096), blk, 0, stream>>>(qkvb, wtsf, dlyi, aggb);
  mfma_gemm<0, 0, 0, 1, 1><<<dim3(512), blk, 0, stream>>>(
      aggb, Wot, bo, x, nullptr, nullptr, xrb, 512, 512, 512, 512, 4);

  // decomp 1 -> s1b bf16
  decomp_b2b<<<dim3(2, 8, 32), blk, 0, stream>>>(xrb, s1b);

  // FFN1: relu(s1b @ W1) -> midb bf16
  mfma_gemm<0, 1, 0, 1, 0><<<dim3(2048), blk, 0, stream>>>(
      s1b, W1t, nullptr, nullptr, nullptr, nullptr, midb, 2048, 512, 512, 512, 16);
  // FFN2 split-K=2 (one dispatch, 1024 blocks)
  mfma_gemm<1, 0, 1, 0, 2><<<dim3(1024), blk, 0, stream>>>(
      midb, W2t, nullptr, nullptr, s1b, s2p, nullptr, 512, 1024, 2048, 2048, 4);

  // decomp 2 over (partial0 + partial1) -> out fp32
  decomp_ff2<<<dim3(2, 8, 32), blk, 0, stream>>>(s2p, s2p + NBLD, out);
}

// Round 7
// 495.872 us; speedup vs baseline: 6.6986x; 1.0481x over previous
//
#include <hip/hip_runtime.h>
#include <math.h>

namespace {
constexpr int kB = 8;
constexpr int kL = 2048;
constexpr int kD = 512;
constexpr int kTopk = 15;
constexpr int kLMask = 2047;
}

typedef unsigned short u16;
using f32x4 = __attribute__((ext_vector_type(4))) float;
using bf16x8 = __attribute__((ext_vector_type(8))) __bf16;

__device__ __forceinline__ u16 f2b(float f) {
  unsigned u = __float_as_uint(f);
  unsigned r = (u + 0x7fffu + ((u >> 16) & 1u)) >> 16;  // RNE
  return (u16)r;
}
__device__ __forceinline__ float b2f(u16 u) {
  return __uint_as_float(((unsigned)u) << 16);
}

typedef __attribute__((address_space(3))) unsigned int lds_u32;
typedef __attribute__((address_space(1))) const unsigned int glb_u32;
__device__ __forceinline__ void gl2lds16(const void* g, void* l) {
  __builtin_amdgcn_global_load_lds((glb_u32*)g, (lds_u32*)l, 16, 0, 0);
}

// ---------------------------------------------------------------------------
// bf16 MFMA GEMM: 128x128 tile, BK=64, global_load_lds staging, swapped-
// operand MFMA so each thread owns 4 CONSECUTIVE columns -> vector epilogue.
// 1-D swizzled grid: XCD = lin%8 owns complete A row-strips (M=16384 fixed).
// SPLIT: grid doubled; split = lin>>9 takes K-half, writes to out + split*M*N.
// RES: 0 none, 1 fp32 (always), 2 bf16 (split 0 only).
// ---------------------------------------------------------------------------
template <int SPLIT, int RELU, int OUTF, int OUTB, int RES>
__global__ __launch_bounds__(256)
void mfma_gemm(const u16* __restrict__ A, const u16* __restrict__ Bt,
               const float* __restrict__ bias, const float* __restrict__ ResF,
               const u16* __restrict__ ResB, float* __restrict__ outF,
               u16* __restrict__ outB, int N, int K, int lda, int ldb, int nbn) {
  __shared__ u16 As[128 * 64];
  __shared__ u16 Bs[128 * 64];
  int lin = blockIdx.x;
  int split = 0;
  if (SPLIT) { split = lin >> 9; lin &= 511; }
  const int xcd = lin & 7;
  const int s = lin >> 3;
  const int q = s / nbn;
  const int bm = xcd * 16 + q;
  const int bn = s - q * nbn;
  const int tid = threadIdx.x;
  const int wave = tid >> 6;
  const int lane = tid & 63;
  const int ln = lane & 15;
  const int quad = lane >> 4;
  const int wm = (wave >> 1) * 64;
  const int wn = (wave & 1) * 64;
  const int srow = tid >> 3;        // 0..31
  const int scol = (tid & 7) * 8;   // 16B chunk within 64-col stripe

  const size_t koff = (size_t)split * K;
  const u16* Ab = A + koff + (size_t)(bm * 128) * lda + scol;
  const u16* Bb = Bt + koff + (size_t)(bn * 128) * ldb + scol;
  char* ldsA = (char*)As + wave * 1024;
  char* ldsB = (char*)Bs + wave * 1024;

  f32x4 acc[4][4];
#pragma unroll
  for (int i = 0; i < 4; ++i)
#pragma unroll
    for (int j = 0; j < 4; ++j) acc[i][j] = (f32x4){0.f, 0.f, 0.f, 0.f};

  for (int k0 = 0; k0 < K; k0 += 64) {
#pragma unroll
    for (int c = 0; c < 4; ++c) {
      gl2lds16(Ab + (size_t)(srow + 32 * c) * lda + k0, ldsA + c * 4096);
      gl2lds16(Bb + (size_t)(srow + 32 * c) * ldb + k0, ldsB + c * 4096);
    }
    __syncthreads();
#pragma unroll
    for (int kk = 0; kk < 2; ++kk) {
      bf16x8 af[4], bfr[4];
#pragma unroll
      for (int i = 0; i < 4; ++i)
        af[i] = *(const bf16x8*)(As + (wm + i * 16 + ln) * 64 + kk * 32 + quad * 8);
#pragma unroll
      for (int j = 0; j < 4; ++j)
        bfr[j] = *(const bf16x8*)(Bs + (wn + j * 16 + ln) * 64 + kk * 32 + quad * 8);
#pragma unroll
      for (int i = 0; i < 4; ++i)
#pragma unroll
        for (int j = 0; j < 4; ++j)
          acc[i][j] = __builtin_amdgcn_mfma_f32_16x16x32_bf16(bfr[j], af[i], acc[i][j], 0, 0, 0);
    }
    __syncthreads();
  }

  // Swapped-operand C layout: row = wm+i*16+ln ; cols = wn+j*16+quad*4 .. +3
  const size_t cbase = (size_t)split * ((size_t)16384 * N);
  const bool res2 = (RES == 2) && (!SPLIT || split == 0);
#pragma unroll
  for (int i = 0; i < 4; ++i) {
    const int row = bm * 128 + wm + i * 16 + ln;
#pragma unroll
    for (int j = 0; j < 4; ++j) {
      const int col = bn * 128 + wn + j * 16 + quad * 4;
      f32x4 v = acc[i][j];
      if (bias) {
        float4 bv = *(const float4*)(bias + col);
        v[0] += bv.x; v[1] += bv.y; v[2] += bv.z; v[3] += bv.w;
      }
      if (RES == 1) {
        float4 rv = *(const float4*)(ResF + (size_t)row * N + col);
        v[0] += rv.x; v[1] += rv.y; v[2] += rv.z; v[3] += rv.w;
      }
      if (RES == 2) {
        if (res2) {
          ushort4 rv = *(const ushort4*)(ResB + (size_t)row * N + col);
          v[0] += b2f(rv.x); v[1] += b2f(rv.y); v[2] += b2f(rv.z); v[3] += b2f(rv.w);
        }
      }
      if (RELU) {
#pragma unroll
        for (int r = 0; r < 4; ++r) v[r] = fmaxf(v[r], 0.f);
      }
      if (OUTF) {
        float4 o = {v[0], v[1], v[2], v[3]};
        *(float4*)(outF + cbase + (size_t)row * N + col) = o;
      }
      if (OUTB) {
        ushort4 o = {f2b(v[0]), f2b(v[1]), f2b(v[2]), f2b(v[3])};
        *(ushort4*)(outB + cbase + (size_t)row * N + col) = o;
      }
    }
  }
}

// ---------------------------------------------------------------------------
// Correlation spectra via packed complex FFT (one block = batch x 4 channels).
// ---------------------------------------------------------------------------
__global__ __launch_bounds__(256)
void fft_corr(const u16* __restrict__ qkv, float* __restrict__ pA,
              float* __restrict__ pB) {
  __shared__ u16 stq[4 * 2048];
  __shared__ u16 stk[4 * 2048];
  __shared__ float re[2048];
  __shared__ float im[2048];
  __shared__ float twc[2047];
  __shared__ float tws[2047];
  const int blk = blockIdx.x;
  const int b = blk & 7;
  const int g = blk >> 3;
  const int t = threadIdx.x;

  for (int e = t; e < 2047; e += 256) {
    const int s = 31 - __clz(e + 1);
    const int m = 1 << s;
    const int j = e + 1 - m;
    float sv, cv;
    __sincosf((float)j * 3.14159265358979323846f / (float)m, &sv, &cv);
    twc[e] = cv;
    tws[e] = sv;
  }
  const u16* qb = qkv + (size_t)b * kL * 1536 + g * 4;
#pragma unroll
  for (int p = 0; p < 8; ++p) {
    const int row = p * 256 + t;
    *(ushort4*)&stq[row * 4] = *(const ushort4*)(qb + (size_t)row * 1536);
    *(ushort4*)&stk[row * 4] = *(const ushort4*)(qb + (size_t)row * 1536 + 512);
  }

  float accA[8], accB[8];
#pragma unroll
  for (int i = 0; i < 8; ++i) { accA[i] = 0.f; accB[i] = 0.f; }

  for (int c = 0; c < 4; ++c) {
    __syncthreads();
#pragma unroll
    for (int p = 0; p < 8; ++p) {
      const int n = p * 256 + t;
      re[n] = b2f(stq[n * 4 + c]);
      im[n] = b2f(stk[n * 4 + c]);
    }
    for (int s = 10; s >= 0; --s) {
      __syncthreads();
      const int m = 1 << s;
      for (int p = 0; p < 4; ++p) {
        const int id = p * 256 + t;
        const int j = id & (m - 1);
        const int i0 = ((id >> s) << (s + 1)) + j;
        const int i1 = i0 + m;
        const int kk = (m - 1) + j;
        const float ar = re[i0], ai = im[i0];
        const float br = re[i1], bi = im[i1];
        re[i0] = ar + br;
        im[i0] = ai + bi;
        const float dr = ar - br, di = ai - bi;
        const float cv = twc[kk], sv = tws[kk];
        re[i1] = dr * cv + di * sv;
        im[i1] = di * cv - dr * sv;
      }
    }
    __syncthreads();
#pragma unroll
    for (int i = 0; i < 8; ++i) {
      const int pos = (i < 4) ? (i * 256 + t) : (1024 + (i - 4) * 256 + t);
      const int f = __brev((unsigned)pos) >> 21;
      if (f <= 1024) {
        const int fm = (2048 - f) & 2047;
        const int pm = __brev((unsigned)fm) >> 21;
        const float zr = re[pos], zi = im[pos];
        const float mr = re[pm], mi = im[pm];
        const float ReQ = 0.5f * (zr + mr);
        const float ImQ = 0.5f * (zi - mi);
        const float ReK = 0.5f * (zi + mi);
        const float ImK = 0.5f * (mr - zr);
        accA[i] += ReQ * ReK;
        accB[i] += ImQ * ImK;
      }
    }
  }
  float* pAb = pA + (size_t)blk * 1025;
  float* pBb = pB + (size_t)blk * 1025;
#pragma unroll
  for (int i = 0; i < 8; ++i) {
    const int pos = (i < 4) ? (i * 256 + t) : (1024 + (i - 4) * 256 + t);
    const int f = __brev((unsigned)pos) >> 21;
    if (f <= 1024) { pAb[f] = accA[i]; pBb[f] = accB[i]; }
  }
}

// sum 128 group partials -> Asp/Bsp. Grid (8 batches, 5 freq chunks).
__global__ __launch_bounds__(256)
void reduceAB(const float* __restrict__ pA, const float* __restrict__ pB,
              float* __restrict__ Asp, float* __restrict__ Bsp) {
  const int b = blockIdx.x;
  const int f = blockIdx.y * 256 + threadIdx.x;
  if (f > 1024) return;
  float sa = 0.f, sb = 0.f;
  for (int g = 0; g < 128; ++g) {
    const size_t idx = (size_t)((g << 3) | b) * 1025 + f;
    sa += pA[idx];
    sb += pB[idx];
  }
  Asp[b * 1025 + f] = sa;
  Bsp[b * 1025 + f] = sb;
}

// meanv = irfft(A - iB)/512 via inverse complex FFT (DIT, bit-rev input).
__global__ __launch_bounds__(256)
void ifft_meanv(const float* __restrict__ Asp, const float* __restrict__ Bsp,
                float* __restrict__ meanv) {
  __shared__ float re[2048];
  __shared__ float im[2048];
  __shared__ float twc[2047];
  __shared__ float tws[2047];
  const int b = blockIdx.x;
  const int t = threadIdx.x;
  for (int e = t; e < 2047; e += 256) {
    const int s = 31 - __clz(e + 1);
    const int m = 1 << s;
    const int j = e + 1 - m;
    float sv, cv;
    __sincosf((float)j * 3.14159265358979323846f / (float)m, &sv, &cv);
    twc[e] = cv;
    tws[e] = sv;
  }
#pragma unroll
  for (int i = 0; i < 8; ++i) {
    const int f = i * 256 + t;
    float Xr, Xi;
    if (f <= 1024) {
      Xr = Asp[b * 1025 + f];
      Xi = (f == 0 || f == 1024) ? 0.f : -Bsp[b * 1025 + f];
    } else {
      const int gg = 2048 - f;
      Xr = Asp[b * 1025 + gg];
      Xi = Bsp[b * 1025 + gg];
    }
    const int pos = __brev((unsigned)f) >> 21;
    re[pos] = Xr;
    im[pos] = Xi;
  }
  for (int s = 0; s <= 10; ++s) {
    __syncthreads();
    const int m = 1 << s;
    for (int p = 0; p < 4; ++p) {
      const int id = p * 256 + t;
      const int j = id & (m - 1);
      const int i0 = ((id >> s) << (s + 1)) + j;
      const int i1 = i0 + m;
      const int kk = (m - 1) + j;
      const float cv = twc[kk], sv = tws[kk];
      const float br = re[i1], bi = im[i1];
      const float tr = br * cv - bi * sv;
      const float ti = bi * cv + br * sv;
      const float ar = re[i0], ai = im[i0];
      re[i0] = ar + tr;
      im[i0] = ai + ti;
      re[i1] = ar - tr;
      im[i1] = ai - ti;
    }
  }
  __syncthreads();
#pragma unroll
  for (int i = 0; i < 8; ++i) {
    const int n = i * 256 + t;
    meanv[b * kL + n] = re[n] * (1.0f / (2048.0f * 512.0f));
  }
}

__global__ __launch_bounds__(256)
void cast_f2b_kernel(const float* __restrict__ X, u16* __restrict__ Y) {
  const int i = (blockIdx.x * 256 + threadIdx.x) * 4;
  float4 v = *(const float4*)(X + i);
  ushort4 o;
  o.x = f2b(v.x); o.y = f2b(v.y); o.z = f2b(v.z); o.w = f2b(v.w);
  *(ushort4*)(Y + i) = o;
}

// 4x 512x512 W[K][N] fp32 -> Wt[N][K] bf16, z-batched
__global__ __launch_bounds__(256)
void transpose4_kernel(const float* __restrict__ W0, const float* __restrict__ W1,
                       const float* __restrict__ W2, const float* __restrict__ W3,
                       u16* __restrict__ dst) {
  __shared__ float t[32][33];
  const int z = blockIdx.z;
  const float* W = z == 0 ? W0 : z == 1 ? W1 : z == 2 ? W2 : W3;
  u16* Wt = dst + (size_t)z * 512 * 512;
  const int k0 = blockIdx.y * 32, n0 = blockIdx.x * 32;
  const int tx = threadIdx.x & 31, ty = threadIdx.x >> 5;
  for (int r = ty; r < 32; r += 8)
    t[r][tx] = W[(size_t)(k0 + r) * 512 + n0 + tx];
  __syncthreads();
  for (int r = ty; r < 32; r += 8)
    Wt[(size_t)(n0 + r) * 512 + k0 + tx] = f2b(t[tx][r]);
}

// generic W[K][N] fp32 -> Wt[N][K] bf16
__global__ __launch_bounds__(256)
void transpose_cast_kernel(const float* __restrict__ W, u16* __restrict__ Wt,
                           int K, int N) {
  __shared__ float t[32][33];
  const int k0 = blockIdx.y * 32, n0 = blockIdx.x * 32;
  const int tx = threadIdx.x & 31, ty = threadIdx.x >> 5;
  for (int r = ty; r < 32; r += 8)
    t[r][tx] = W[(size_t)(k0 + r) * N + n0 + tx];
  __syncthreads();
  for (int r = ty; r < 32; r += 8)
    Wt[(size_t)(n0 + r) * K + k0 + tx] = f2b(t[tx][r]);
}

__global__ void concat_bias_kernel(const float* __restrict__ bq,
                                   const float* __restrict__ bk,
                                   const float* __restrict__ bv,
                                   float* __restrict__ o) {
  const int i = blockIdx.x * 256 + threadIdx.x;
  const float* s = i < 512 ? bq : (i < 1024 ? bk : bv);
  o[i] = s[i & 511];
}

// stage 1: per-256-chunk local top-15. Grid (8 chunks, 8 batches).
__global__ __launch_bounds__(256)
void topk1_kernel(const float* __restrict__ meanv, float* __restrict__ candv,
                  int* __restrict__ candi) {
  __shared__ float f[256];
  __shared__ float rv[256];
  __shared__ int ri[256];
  const int chunk = blockIdx.x;
  const int b = blockIdx.y;
  const int t = threadIdx.x;
  const int gi = chunk * 256 + t;
  f[t] = meanv[b * kL + gi];
  __syncthreads();
  const int obase = (b * 8 + chunk) * kTopk;
  for (int round = 0; round < kTopk; ++round) {
    rv[t] = f[t];
    ri[t] = gi;
    __syncthreads();
    for (int s = 128; s > 0; s >>= 1) {
      if (t < s) {
        const float v2 = rv[t + s];
        const int i2 = ri[t + s];
        if (v2 > rv[t] || (v2 == rv[t] && i2 < ri[t])) { rv[t] = v2; ri[t] = i2; }
      }
      __syncthreads();
    }
    if (t == 0) {
      candv[obase + round] = rv[0];
      candi[obase + round] = ri[0];
      f[ri[0] & 255] = -INFINITY;
    }
    __syncthreads();
  }
}

// stage 2: merge 8x15=120 candidates -> global top-15 + softmax. Grid (8).
__global__ __launch_bounds__(128)
void topk2_kernel(const float* __restrict__ candv, const int* __restrict__ candi,
                  float* __restrict__ wts, int* __restrict__ dly) {
  __shared__ float f[128];
  __shared__ int fi[128];
  __shared__ float rv[128];
  __shared__ int ri[128];
  __shared__ float topv[kTopk];
  __shared__ int topi[kTopk];
  const int b = blockIdx.x;
  const int t = threadIdx.x;
  if (t < 120) {
    f[t] = candv[b * 120 + t];
    fi[t] = candi[b * 120 + t];
  } else {
    f[t] = -INFINITY;
    fi[t] = 1 << 30;
  }
  __syncthreads();
  for (int round = 0; round < kTopk; ++round) {
    rv[t] = f[t];
    ri[t] = t;
    __syncthreads();
    for (int s = 64; s > 0; s >>= 1) {
      if (t < s) {
        const float v2 = rv[t + s];
        const int i2 = ri[t + s];
        if (v2 > rv[t] || (v2 == rv[t] && fi[i2] < fi[ri[t]])) { rv[t] = v2; ri[t] = i2; }
      }
      __syncthreads();
    }
    if (t == 0) {
      topv[round] = rv[0];
      topi[round] = fi[ri[0]];
      f[ri[0]] = -INFINITY;
    }
    __syncthreads();
  }
  if (t == 0) {
    const float m = topv[0];
    float sum = 0.f;
    float e[kTopk];
    for (int i = 0; i < kTopk; ++i) { e[i] = expf(topv[i] - m); sum += e[i]; }
    for (int i = 0; i < kTopk; ++i) {
      wts[b * 16 + i] = e[i] / sum;
      dly[b * 16 + i] = topi[i];
    }
  }
}

// attn_in[b,l,c] = sum_t w_t * v[b,(l+delay_t)%L,c]; 1-D grid, batch = lin%8
__global__ __launch_bounds__(256)
void agg_kernel(const u16* __restrict__ qkv, const float* __restrict__ wts,
                const int* __restrict__ dly, u16* __restrict__ out) {
  __shared__ float w[16];
  __shared__ int dl[16];
  const int lin = blockIdx.x;
  const int b = lin & 7;
  if (threadIdx.x < kTopk) {
    w[threadIdx.x] = wts[b * 16 + threadIdx.x];
    dl[threadIdx.x] = dly[b * 16 + threadIdx.x];
  }
  __syncthreads();
  const int l = (lin >> 3) * 4 + (threadIdx.x >> 6);
  const int co = (threadIdx.x & 63) * 8;
  const u16* vb = qkv + (size_t)b * kL * 1536 + 1024 + co;
  float a[8] = {0.f, 0.f, 0.f, 0.f, 0.f, 0.f, 0.f, 0.f};
  for (int t = 0; t < kTopk; ++t) {
    const int row = (l + dl[t]) & kLMask;
    float4 rv = *(const float4*)(vb + (size_t)row * 1536);
    const u16* p = (const u16*)&rv;
    const float wt = w[t];
#pragma unroll
    for (int e = 0; e < 8; ++e) a[e] += wt * b2f(p[e]);
  }
  u16 ob[8];
#pragma unroll
  for (int e = 0; e < 8; ++e) ob[e] = f2b(a[e]);
  *(float4*)(out + ((size_t)b * kL + l) * kD + co) = *(const float4*)ob;
}

// decomp, bf16 in -> bf16 out (streaming 25-tap clamped MA)
__global__ __launch_bounds__(256)
void decomp_b2b(const u16* __restrict__ X, u16* __restrict__ OB) {
  const int c = blockIdx.x * 256 + threadIdx.x;
  const int b = blockIdx.y;
  const int l0 = blockIdx.z * 64;
  const u16* base = X + (size_t)b * kL * kD + c;
  float sum = 0.f;
#pragma unroll
  for (int m = -12; m <= 12; ++m) {
    int lm = l0 + m;
    lm = lm < 0 ? 0 : (lm > kL - 1 ? kL - 1 : lm);
    sum += b2f(base[(size_t)lm * kD]);
  }
#pragma unroll 4
  for (int l = l0; l < l0 + 64; ++l) {
    const float val = b2f(base[(size_t)l * kD]);
    OB[((size_t)b * kL + l) * kD + c] = f2b(val - sum * (1.0f / 25.0f));
    const int la = l + 13 > kL - 1 ? kL - 1 : l + 13;
    const int lr = l - 12 < 0 ? 0 : l - 12;
    sum += b2f(base[(size_t)la * kD]) - b2f(base[(size_t)lr * kD]);
  }
}

// decomp of (X1+X2), fp32 -> fp32 out
__global__ __launch_bounds__(256)
void decomp_ff2(const float* __restrict__ X1, const float* __restrict__ X2,
                float* __restrict__ OF) {
  const int c = blockIdx.x * 256 + threadIdx.x;
  const int b = blockIdx.y;
  const int l0 = blockIdx.z * 64;
  const size_t off = (size_t)b * kL * kD + c;
  const float* b1 = X1 + off;
  const float* b2 = X2 + off;
  float sum = 0.f;
#pragma unroll
  for (int m = -12; m <= 12; ++m) {
    int lm = l0 + m;
    lm = lm < 0 ? 0 : (lm > kL - 1 ? kL - 1 : lm);
    sum += b1[(size_t)lm * kD] + b2[(size_t)lm * kD];
  }
#pragma unroll 4
  for (int l = l0; l < l0 + 64; ++l) {
    const float val = b1[(size_t)l * kD] + b2[(size_t)l * kD];
    OF[((size_t)b * kL + l) * kD + c] = val - sum * (1.0f / 25.0f);
    const int la = l + 13 > kL - 1 ? kL - 1 : l + 13;
    const int lr = l - 12 < 0 ? 0 : l - 12;
    sum += b1[(size_t)la * kD] + b2[(size_t)la * kD]
         - b1[(size_t)lr * kD] - b2[(size_t)lr * kD];
  }
}

extern "C" void kernel_launch(void* const* d_in, const int* in_sizes, int n_in,
                              void* d_out, int out_size, void* d_ws, size_t ws_size,
                              hipStream_t stream) {
  const float* x  = (const float*)d_in[0];
  const float* Wq = (const float*)d_in[1];
  const float* bq = (const float*)d_in[2];
  const float* Wk = (const float*)d_in[3];
  const float* bk = (const float*)d_in[4];
  const float* Wv = (const float*)d_in[5];
  const float* bv = (const float*)d_in[6];
  const float* Wo = (const float*)d_in[7];
  const float* bo = (const float*)d_in[8];
  const float* W1 = (const float*)d_in[9];
  const float* W2 = (const float*)d_in[10];
  float* out = (float*)d_out;

  const size_t MiB = 1u << 20;
  const size_t NBLD = (size_t)kB * kL * kD;  // 8,388,608
  char* base = (char*)d_ws;
  u16*   qkvb  = (u16*)(base);               // [0,48)
  u16*   xb    = (u16*)(base + 48 * MiB);    // [48,64) ; aggb aliases
  u16*   aggb  = xb;
  u16*   xrb   = (u16*)(base + 64 * MiB);    // [64,80)
  u16*   s1b   = (u16*)(base + 80 * MiB);    // [80,96)
  u16*   midb  = (u16*)(base + 96 * MiB);    // [96,160)
  float* s2p   = (float*)(base);             // [0,64) after qkvb/aggb dead
  u16*   Wqkvt = (u16*)(base + 160 * MiB);   // 2 MiB (incl Wot as slot 3)
  u16*   Wot   = Wqkvt + 3 * 512 * 512;
  u16*   W1t   = (u16*)(base + 162 * MiB);   // 2 MiB
  u16*   W2t   = (u16*)(base + 164 * MiB);   // 2 MiB
  float* bqkv  = (float*)(base + 166 * MiB);
  float* Asp   = bqkv + 2048;                // 8 x 1025
  float* Bsp   = Asp + kB * 1025;
  float* meanv = Bsp + kB * 1025;            // 8 x 2048
  float* wtsf  = meanv + kB * kL;
  int*   dlyi  = (int*)(wtsf + kB * 16);
  float* candv = (float*)(dlyi + kB * 16);   // 8*8*15
  int*   candi = (int*)(candv + kB * 8 * kTopk);
  float* pA    = (float*)(base + 167 * MiB); // 1024 x 1025 (~4 MiB)
  float* pB    = (float*)(base + 172 * MiB); // 1024 x 1025

  const dim3 blk(256);

  // input cast + weight prep
  cast_f2b_kernel<<<(int)(NBLD / 1024), blk, 0, stream>>>(x, xb);
  transpose4_kernel<<<dim3(16, 16, 4), blk, 0, stream>>>(Wq, Wk, Wv, Wo, Wqkvt);
  transpose_cast_kernel<<<dim3(64, 16), blk, 0, stream>>>(W1, W1t, 512, 2048);
  transpose_cast_kernel<<<dim3(16, 64), blk, 0, stream>>>(W2, W2t, 2048, 512);
  concat_bias_kernel<<<dim3(6), blk, 0, stream>>>(bq, bk, bv, bqkv);

  // fused QKV projection -> qkvb bf16
  mfma_gemm<0, 0, 0, 1, 0><<<dim3(1536), blk, 0, stream>>>(
      xb, Wqkvt, bqkv, nullptr, nullptr, nullptr, qkvb, 1536, 512, 512, 512, 12);

  // correlation spectra via packed FFTs
  fft_corr<<<dim3(1024), blk, 0, stream>>>(qkvb, pA, pB);
  reduceAB<<<dim3(8, 5), blk, 0, stream>>>(pA, pB, Asp, Bsp);
  ifft_meanv<<<dim3(8), blk, 0, stream>>>(Asp, Bsp, meanv);

  topk1_kernel<<<dim3(8, 8), blk, 0, stream>>>(meanv, candv, candi);
  topk2_kernel<<<dim3(8), dim3(128), 0, stream>>>(candv, candi, wtsf, dlyi);

  // delay aggregation -> aggb bf16 ; Wo + bias + residual(x) -> xrb bf16
  agg_kernel<<<dim3(4096), blk, 0, stream>>>(qkvb, wtsf, dlyi, aggb);
  mfma_gemm<0, 0, 0, 1, 1><<<dim3(512), blk, 0, stream>>>(
      aggb, Wot, bo, x, nullptr, nullptr, xrb, 512, 512, 512, 512, 4);

  // decomp 1 -> s1b bf16
  decomp_b2b<<<dim3(2, 8, 32), blk, 0, stream>>>(xrb, s1b);

  // FFN1: relu(s1b @ W1) -> midb bf16
  mfma_gemm<0, 1, 0, 1, 0><<<dim3(2048), blk, 0, stream>>>(
      s1b, W1t, nullptr, nullptr, nullptr, nullptr, midb, 2048, 512, 512, 512, 16);
  // FFN2 split-K=2 (one dispatch, 1024 blocks)
  mfma_gemm<1, 0, 1, 0, 2><<<dim3(1024), blk, 0, stream>>>(
      midb, W2t, nullptr, nullptr, s1b, s2p, nullptr, 512, 1024, 2048, 2048, 4);

  // decomp 2 over (partial0 + partial1) -> out fp32
  decomp_ff2<<<dim3(2, 8, 32), blk, 0, stream>>>(s2p, s2p + NBLD, out);
}